// Round 8
// baseline (236.260 us; speedup 1.0000x reference)
//
#include <hip/hip_runtime.h>
#include <math.h>

#define TT 4096
#define DM 512
#define NH 8
#define HD 64
#define WN (DM * DM)   // 262144 elements per weight matrix

typedef float f32x4 __attribute__((ext_vector_type(4)));
typedef short short8 __attribute__((ext_vector_type(8)));
typedef _Float16 half8 __attribute__((ext_vector_type(8)));

#define GLD16(gp, lp) __builtin_amdgcn_global_load_lds( \
    (const __attribute__((address_space(1))) void*)(gp), \
    (__attribute__((address_space(3))) void*)(lp), 16, 0, 0)

static __device__ __forceinline__ float bf2f(unsigned short h) {
    unsigned int u = ((unsigned int)h) << 16;
    return __builtin_bit_cast(float, u);
}
// bf16 truncation split (for proj X/W staging)
static __device__ __forceinline__ void splitbf(float x, unsigned short& hi, unsigned short& lo) {
    unsigned int u = __builtin_bit_cast(unsigned int, x);
    hi = (unsigned short)(u >> 16);
    float r = x - bf2f(hi);
    lo = (unsigned short)(__builtin_bit_cast(unsigned int, r) >> 16);
}
// fp16 RTN split (for Q/K outputs): x = hi + lo to ~2^-22 rel
static __device__ __forceinline__ void splitf16(float x, unsigned short& hi, unsigned short& lo) {
    _Float16 h = (_Float16)x;
    hi = __builtin_bit_cast(unsigned short, h);
    _Float16 l = (_Float16)(x - (float)h);
    lo = __builtin_bit_cast(unsigned short, l);
}
// Q-row permutation: LDS row rho holds global q-row qperm(rho). Maps MFMA C-rows
// (lg*4+r) onto PV B-frag k-slots (lg*8+j) so P stays in registers.
static __device__ __forceinline__ int qperm(int r) {
    return ((r >> 5) << 5) | (((r >> 2) & 3) << 3) | (((r >> 4) & 1) << 2) | (r & 3);
}

// ---------------------------------------------------------------------------
// Pre-split the three weight matrices into bf16 hi/lo. grid (128, 3), 256 thr.
// ---------------------------------------------------------------------------
__global__ __launch_bounds__(256) void wsplit(
    const float* __restrict__ Wq, const float* __restrict__ Wk, const float* __restrict__ Wv,
    unsigned short* __restrict__ Whi, unsigned short* __restrict__ Wlo)
{
    const int z = blockIdx.y;
    const float* __restrict__ src = (z == 0) ? Wq : (z == 1) ? Wk : Wv;
    const int i = (blockIdx.x * 256 + threadIdx.x) * 8;
    float4 a = *(const float4*)&src[i];
    float4 b = *(const float4*)&src[i + 4];
    float v[8] = {a.x, a.y, a.z, a.w, b.x, b.y, b.z, b.w};
    unsigned short hb[8], lb[8];
    #pragma unroll
    for (int k = 0; k < 8; ++k) splitbf(v[k], hb[k], lb[k]);
    uint4 hv, lv;
    hv.x = (unsigned int)hb[0] | ((unsigned int)hb[1] << 16);
    hv.y = (unsigned int)hb[2] | ((unsigned int)hb[3] << 16);
    hv.z = (unsigned int)hb[4] | ((unsigned int)hb[5] << 16);
    hv.w = (unsigned int)hb[6] | ((unsigned int)hb[7] << 16);
    lv.x = (unsigned int)lb[0] | ((unsigned int)lb[1] << 16);
    lv.y = (unsigned int)lb[2] | ((unsigned int)lb[3] << 16);
    lv.z = (unsigned int)lb[4] | ((unsigned int)lb[5] << 16);
    lv.w = (unsigned int)lb[6] | ((unsigned int)lb[7] << 16);
    *(uint4*)&Whi[(size_t)z * WN + i] = hv;
    *(uint4*)&Wlo[(size_t)z * WN + i] = lv;
}

// ---------------------------------------------------------------------------
// Projection via 3-term split-bf16 MFMA. Y = X @ W^T + bias.
// grid (M/128, 512/64, 3), 256 thr (4 waves), BM=128 BN=64 BK=64.
//   z=0: Q -> fp16 (Qhi,Qlo), pre-scaled 0.125
//   z=1: K -> fp16 (Khi,Klo)
//   z=2: V -> single fp16, transposed [b][h][d][T]
// ---------------------------------------------------------------------------
__global__ __launch_bounds__(256, 2) void proj_mfma(
    const float* __restrict__ X,
    const unsigned short* __restrict__ Whi, const unsigned short* __restrict__ Wlo,
    const float* __restrict__ bq, const float* __restrict__ bk, const float* __restrict__ bv,
    unsigned short* __restrict__ Qhi, unsigned short* __restrict__ Qlo,
    unsigned short* __restrict__ Khi, unsigned short* __restrict__ Klo,
    unsigned short* __restrict__ Vt)
{
    const int z = blockIdx.z;
    const int m0 = blockIdx.x * 128;
    const int n0 = blockIdx.y * 64;
    const int tid = threadIdx.x;
    const int wid = tid >> 6, lane = tid & 63;
    const int lg = lane >> 4, lr = lane & 15;

    __shared__ __attribute__((aligned(16))) unsigned short smem[384 * 72];
    auto Xh  = (unsigned short(*)[72])(smem);
    auto Xl  = (unsigned short(*)[72])(smem + 128 * 72);
    auto Wh2 = (unsigned short(*)[72])(smem + 256 * 72);
    auto Wl2 = (unsigned short(*)[72])(smem + 320 * 72);

    const unsigned short* __restrict__ Wh = Whi + (size_t)z * WN;
    const unsigned short* __restrict__ Wl = Wlo + (size_t)z * WN;

    f32x4 acc[2][4];
    #pragma unroll
    for (int rt = 0; rt < 2; ++rt)
        #pragma unroll
        for (int nt = 0; nt < 4; ++nt) acc[rt][nt] = (f32x4){0.f, 0.f, 0.f, 0.f};

    const int xr = tid >> 1;
    const int xc = (tid & 1) * 32;

    for (int k0 = 0; k0 < DM; k0 += 64) {
        #pragma unroll
        for (int w = 0; w < 4; ++w) {
            float4 fa = *(const float4*)&X[(size_t)(m0 + xr) * DM + k0 + xc + w * 8];
            float4 fb = *(const float4*)&X[(size_t)(m0 + xr) * DM + k0 + xc + w * 8 + 4];
            float v[8] = {fa.x, fa.y, fa.z, fa.w, fb.x, fb.y, fb.z, fb.w};
            unsigned short hb[8], lb[8];
            #pragma unroll
            for (int k = 0; k < 8; ++k) splitbf(v[k], hb[k], lb[k]);
            uint4 hv, lv;
            hv.x = (unsigned int)hb[0] | ((unsigned int)hb[1] << 16);
            hv.y = (unsigned int)hb[2] | ((unsigned int)hb[3] << 16);
            hv.z = (unsigned int)hb[4] | ((unsigned int)hb[5] << 16);
            hv.w = (unsigned int)hb[6] | ((unsigned int)hb[7] << 16);
            lv.x = (unsigned int)lb[0] | ((unsigned int)lb[1] << 16);
            lv.y = (unsigned int)lb[2] | ((unsigned int)lb[3] << 16);
            lv.z = (unsigned int)lb[4] | ((unsigned int)lb[5] << 16);
            lv.w = (unsigned int)lb[6] | ((unsigned int)lb[7] << 16);
            *(uint4*)&Xh[xr][xc + w * 8] = hv;
            *(uint4*)&Xl[xr][xc + w * 8] = lv;
        }
        #pragma unroll
        for (int it = 0; it < 2; ++it) {
            int i2 = it * 256 + tid;
            int fr = i2 >> 3, ch = i2 & 7;
            *(int4*)&Wh2[fr][ch * 8] = *(const int4*)&Wh[(size_t)(n0 + fr) * DM + k0 + ch * 8];
            *(int4*)&Wl2[fr][ch * 8] = *(const int4*)&Wl[(size_t)(n0 + fr) * DM + k0 + ch * 8];
        }
        __syncthreads();

        __builtin_amdgcn_s_setprio(1);
        #pragma unroll
        for (int kc = 0; kc < 2; ++kc) {
            short8 xa[2][2];
            #pragma unroll
            for (int rt = 0; rt < 2; ++rt) {
                xa[rt][0] = __builtin_bit_cast(short8, *(const int4*)&Xh[wid * 32 + rt * 16 + lr][kc * 32 + lg * 8]);
                xa[rt][1] = __builtin_bit_cast(short8, *(const int4*)&Xl[wid * 32 + rt * 16 + lr][kc * 32 + lg * 8]);
            }
            #pragma unroll
            for (int nt = 0; nt < 4; ++nt) {
                short8 wh = __builtin_bit_cast(short8, *(const int4*)&Wh2[nt * 16 + lr][kc * 32 + lg * 8]);
                short8 wl = __builtin_bit_cast(short8, *(const int4*)&Wl2[nt * 16 + lr][kc * 32 + lg * 8]);
                #pragma unroll
                for (int rt = 0; rt < 2; ++rt) {
                    acc[rt][nt] = __builtin_amdgcn_mfma_f32_16x16x32_bf16(xa[rt][0], wh, acc[rt][nt], 0, 0, 0);
                    acc[rt][nt] = __builtin_amdgcn_mfma_f32_16x16x32_bf16(xa[rt][1], wh, acc[rt][nt], 0, 0, 0);
                    acc[rt][nt] = __builtin_amdgcn_mfma_f32_16x16x32_bf16(xa[rt][0], wl, acc[rt][nt], 0, 0, 0);
                }
            }
        }
        __builtin_amdgcn_s_setprio(0);
        __syncthreads();
    }

    if (z < 2) {
        const float* __restrict__ bias = (z == 0) ? bq : bk;
        unsigned short* __restrict__ Hi = (z == 0) ? Qhi : Khi;
        unsigned short* __restrict__ Lo = (z == 0) ? Qlo : Klo;
        const float sc = (z == 0) ? 0.125f : 1.0f;
        #pragma unroll
        for (int nt = 0; nt < 4; ++nt) {
            int n = n0 + nt * 16 + lr;
            float bv_ = bias[n];
            #pragma unroll
            for (int rt = 0; rt < 2; ++rt)
                #pragma unroll
                for (int r = 0; r < 4; ++r) {
                    int m = m0 + wid * 32 + rt * 16 + lg * 4 + r;
                    float y = (acc[rt][nt][r] + bv_) * sc;
                    unsigned short hb, lb;
                    splitf16(y, hb, lb);
                    Hi[(size_t)m * DM + n] = hb;
                    Lo[(size_t)m * DM + n] = lb;
                }
        }
    } else {
        // V: single fp16, bounce through LDS, write transposed [b][h][d][T]
        unsigned short* Tk = (unsigned short*)smem;   // [64][136]
        #pragma unroll
        for (int nt = 0; nt < 4; ++nt) {
            int d = nt * 16 + lr;
            float bv_ = bv[n0 + d];
            #pragma unroll
            for (int rt = 0; rt < 2; ++rt)
                #pragma unroll
                for (int r = 0; r < 4; ++r) {
                    int t = wid * 32 + rt * 16 + lg * 4 + r;
                    float y = acc[rt][nt][r] + bv_;
                    Tk[d * 136 + t] = __builtin_bit_cast(unsigned short, (_Float16)y);
                }
        }
        __syncthreads();
        const int dl = tid >> 2, tq = tid & 3;
        const int bb = m0 >> 12, t0 = m0 & (TT - 1), h = n0 >> 6;
        size_t obase = ((size_t)((bb * NH + h) * HD + dl)) * TT + t0 + tq * 32;
        unsigned int w[16];
        #pragma unroll
        for (int k = 0; k < 16; ++k)
            w[k] = (unsigned int)Tk[dl * 136 + tq * 32 + 2 * k]
                 | ((unsigned int)Tk[dl * 136 + tq * 32 + 2 * k + 1] << 16);
        #pragma unroll
        for (int j = 0; j < 4; ++j) {
            uint4 wv = {w[4 * j], w[4 * j + 1], w[4 * j + 2], w[4 * j + 3]};
            *(uint4*)&Vt[obase + j * 8] = wv;
        }
    }
}

// ---------------------------------------------------------------------------
// Flash attention, fp16 path, 2-wave blocks for TLP. S^T = mfma(Q,K) 3-term;
// PV single-term fp16 (P scaled by 2048, cancels in oacc/l). 32 krows/wave,
// 64 krows/block, grid 1024 -> 6 blocks/CU (24KB LDS each), 12 waves/CU.
// Staging: global_load_lds, linear LDS, pre-swizzled source.
// ---------------------------------------------------------------------------
__global__ __launch_bounds__(128, 2) void attn_mfma(
    const unsigned short* __restrict__ Qhi, const unsigned short* __restrict__ Qlo,
    const unsigned short* __restrict__ Khi, const unsigned short* __restrict__ Klo,
    const unsigned short* __restrict__ Vt,
    float* __restrict__ Out)
{
    const int flat = blockIdx.x;
    const int bh = flat & 15;                 // XCD-grouping: same h -> same XCD
    const int r0 = (flat >> 4) * 64;
    const int b = bh >> 3, h = bh & 7;
    const int tid = threadIdx.x;
    const int wid = tid >> 6, lane = tid & 63;
    const int lg = lane >> 4, lr = lane & 15;
    const int wr0 = r0 + wid * 32;

    __shared__ __attribute__((aligned(16))) unsigned short Qs[128][64]; // perm q rows: hi 0-63, lo 64-127
    __shared__ __attribute__((aligned(16))) unsigned short Vs[64][64];  // V^T rows d (single fp16)

    const size_t qbase = (size_t)b * TT * DM + h * HD;
    const size_t vbase = ((size_t)(b * NH + h)) * HD * TT;

    // K fragments resident in registers: [rowtile][kc][hi/lo]
    half8 kf[2][2][2];
    #pragma unroll
    for (int rt = 0; rt < 2; ++rt)
        #pragma unroll
        for (int kc = 0; kc < 2; ++kc) {
            size_t g = qbase + (size_t)(wr0 + rt * 16 + lr) * DM + kc * 32 + lg * 8;
            kf[rt][kc][0] = __builtin_bit_cast(half8, *(const int4*)&Khi[g]);
            kf[rt][kc][1] = __builtin_bit_cast(half8, *(const int4*)&Klo[g]);
        }

    float m_s[2], l_s[2];
    f32x4 oacc[2][4];
    #pragma unroll
    for (int rt = 0; rt < 2; ++rt) {
        m_s[rt] = -INFINITY; l_s[rt] = 0.f;
        #pragma unroll
        for (int dt = 0; dt < 4; ++dt) oacc[rt][dt] = (f32x4){0.f, 0.f, 0.f, 0.f};
    }

    for (int c0 = 0; c0 < TT; c0 += 64) {
        // ---- stage Q hi/lo (8x) and V (4x) via global_load_lds, swizzled src
        #pragma unroll
        for (int it = 0; it < 8; ++it) {
            int gi = it * 128 + tid;
            int fr = gi >> 3;
            int ch = (gi & 7) ^ (fr & 7);
            const unsigned short* qsrc = (fr < 64) ? Qhi : Qlo;
            GLD16(&qsrc[qbase + (size_t)(c0 + qperm(fr & 63)) * DM + ch * 8],
                  (char*)&Qs[0][0] + (it * 128 + wid * 64) * 16);
        }
        #pragma unroll
        for (int it = 0; it < 4; ++it) {
            int gi = it * 128 + tid;
            int fr = gi >> 3;
            int ch = (gi & 7) ^ (fr & 7);
            GLD16(&Vt[vbase + (size_t)fr * TT + c0 + ch * 8],
                  (char*)&Vs[0][0] + (it * 128 + wid * 64) * 16);
        }
        __syncthreads();

        // ---- S^T = Q @ K^T, 3-term fp16 split
        f32x4 sacc[2][4];
        #pragma unroll
        for (int rt = 0; rt < 2; ++rt)
            #pragma unroll
            for (int qt = 0; qt < 4; ++qt) sacc[rt][qt] = (f32x4){0.f, 0.f, 0.f, 0.f};
        __builtin_amdgcn_s_setprio(1);
        #pragma unroll
        for (int kc = 0; kc < 2; ++kc) {
            #pragma unroll
            for (int qt = 0; qt < 4; ++qt) {
                int row = qt * 16 + lr;
                int so = ((kc * 4 + lg) ^ (row & 7)) * 16;
                half8 qh = __builtin_bit_cast(half8, *(const int4*)((const char*)&Qs[row][0] + so));
                half8 ql = __builtin_bit_cast(half8, *(const int4*)((const char*)&Qs[64 + row][0] + so));
                #pragma unroll
                for (int rt = 0; rt < 2; ++rt) {
                    sacc[rt][qt] = __builtin_amdgcn_mfma_f32_16x16x32_f16(qh, kf[rt][kc][0], sacc[rt][qt], 0, 0, 0);
                    sacc[rt][qt] = __builtin_amdgcn_mfma_f32_16x16x32_f16(ql, kf[rt][kc][0], sacc[rt][qt], 0, 0, 0);
                    sacc[rt][qt] = __builtin_amdgcn_mfma_f32_16x16x32_f16(qh, kf[rt][kc][1], sacc[rt][qt], 0, 0, 0);
                }
            }
        }
        __builtin_amdgcn_s_setprio(0);

        // ---- online softmax per krow (lane-local col) + fp16 pack, scaled e^7.62
        unsigned int hp[2][4][2];
        #pragma unroll
        for (int rt = 0; rt < 2; ++rt) {
            float mx = -INFINITY;
            #pragma unroll
            for (int qt = 0; qt < 4; ++qt)
                #pragma unroll
                for (int r = 0; r < 4; ++r) mx = fmaxf(mx, sacc[rt][qt][r]);
            mx = fmaxf(mx, __shfl_xor(mx, 16));
            mx = fmaxf(mx, __shfl_xor(mx, 32));
            float nm = fmaxf(m_s[rt], mx);
            float al = __expf(m_s[rt] - nm);
            const float nmb = nm - 7.6246190f;       // ln(2048): p' = 2048*p
            float sum = 0.f;
            #pragma unroll
            for (int qt = 0; qt < 4; ++qt)
                #pragma unroll
                for (int r = 0; r < 4; ++r) {
                    float p = __expf(sacc[rt][qt][r] - nmb);
                    sacc[rt][qt][r] = p;
                    sum += p;
                }
            sum += __shfl_xor(sum, 16);
            sum += __shfl_xor(sum, 32);
            m_s[rt] = nm;
            l_s[rt] = l_s[rt] * al + sum;
            #pragma unroll
            for (int qt = 0; qt < 4; ++qt)
                #pragma unroll
                for (int pp = 0; pp < 2; ++pp)
                    hp[rt][qt][pp] = __builtin_bit_cast(unsigned int,
                        __builtin_amdgcn_cvt_pkrtz(sacc[rt][qt][2 * pp], sacc[rt][qt][2 * pp + 1]));
            #pragma unroll
            for (int dt = 0; dt < 4; ++dt)
                #pragma unroll
                for (int r = 0; r < 4; ++r) oacc[rt][dt][r] *= al;
        }

        // ---- out^T += V^T @ P, single fp16 term
        __builtin_amdgcn_s_setprio(1);
        #pragma unroll
        for (int c = 0; c < 2; ++c) {
            half8 pf[2];
            #pragma unroll
            for (int rt = 0; rt < 2; ++rt) {
                int4 ph4 = {(int)hp[rt][2 * c][0], (int)hp[rt][2 * c][1],
                            (int)hp[rt][2 * c + 1][0], (int)hp[rt][2 * c + 1][1]};
                pf[rt] = __builtin_bit_cast(half8, ph4);
            }
            #pragma unroll
            for (int dt = 0; dt < 4; ++dt) {
                int row = dt * 16 + lr;
                int so = ((c * 4 + lg) ^ (row & 7)) * 16;
                half8 vh = __builtin_bit_cast(half8, *(const int4*)((const char*)&Vs[row][0] + so));
                #pragma unroll
                for (int rt = 0; rt < 2; ++rt)
                    oacc[rt][dt] = __builtin_amdgcn_mfma_f32_16x16x32_f16(vh, pf[rt], oacc[rt][dt], 0, 0, 0);
            }
        }
        __builtin_amdgcn_s_setprio(0);
        __syncthreads();
    }

    // epilogue: out[krow][d] = oacc / l  (scale 2048 cancels)
    #pragma unroll
    for (int rt = 0; rt < 2; ++rt) {
        float inv = __builtin_amdgcn_rcpf(l_s[rt]);
        int row = wr0 + rt * 16 + lr;
        #pragma unroll
        for (int dt = 0; dt < 4; ++dt)
            #pragma unroll
            for (int r = 0; r < 4; ++r)
                Out[((size_t)(b * TT + row)) * DM + h * HD + dt * 16 + lg * 4 + r] =
                    oacc[rt][dt][r] * inv;
    }
}

// ---------------------------------------------------------------------------
extern "C" void kernel_launch(void* const* d_in, const int* in_sizes, int n_in,
                              void* d_out, int out_size, void* d_ws, size_t ws_size,
                              hipStream_t stream)
{
    const float* x  = (const float*)d_in[0];
    const float* Wk = (const float*)d_in[1];
    const float* bk = (const float*)d_in[2];
    const float* Wq = (const float*)d_in[3];
    const float* bq = (const float*)d_in[4];
    const float* Wv = (const float*)d_in[5];
    const float* bv = (const float*)d_in[6];
    float* out = (float*)d_out;

    const size_t SZ = (size_t)2 * TT * DM;
    unsigned short* Qhi = (unsigned short*)d_ws;
    unsigned short* Qlo = Qhi + SZ;
    unsigned short* Khi = Qlo + SZ;
    unsigned short* Klo = Khi + SZ;
    unsigned short* Vt  = Klo + SZ;
    unsigned short* Whi = Vt + SZ;
    unsigned short* Wlo = Whi + (size_t)3 * WN;

    wsplit<<<dim3(WN / 2048, 3), dim3(256), 0, stream>>>(Wq, Wk, Wv, Whi, Wlo);

    dim3 pgrid(2 * TT / 128, DM / 64, 3);
    proj_mfma<<<pgrid, dim3(256), 0, stream>>>(x, Whi, Wlo, bq, bk, bv,
                                               Qhi, Qlo, Khi, Klo, Vt);

    attn_mfma<<<dim3(1024), dim3(128), 0, stream>>>(Qhi, Qlo, Khi, Klo, Vt, out);
}

// Round 9
// 231.763 us; speedup vs baseline: 1.0194x; 1.0194x over previous
//
#include <hip/hip_runtime.h>
#include <math.h>

#define TT 4096
#define DM 512
#define NH 8
#define HD 64
#define WN (DM * DM)   // 262144 elements per weight matrix

typedef float f32x4 __attribute__((ext_vector_type(4)));
typedef short short8 __attribute__((ext_vector_type(8)));
typedef _Float16 half8 __attribute__((ext_vector_type(8)));

#define GLD16(gp, lp) __builtin_amdgcn_global_load_lds( \
    (const __attribute__((address_space(1))) void*)(gp), \
    (__attribute__((address_space(3))) void*)(lp), 16, 0, 0)

static __device__ __forceinline__ float bf2f(unsigned short h) {
    unsigned int u = ((unsigned int)h) << 16;
    return __builtin_bit_cast(float, u);
}
// bf16 truncation split (for proj X/W staging)
static __device__ __forceinline__ void splitbf(float x, unsigned short& hi, unsigned short& lo) {
    unsigned int u = __builtin_bit_cast(unsigned int, x);
    hi = (unsigned short)(u >> 16);
    float r = x - bf2f(hi);
    lo = (unsigned short)(__builtin_bit_cast(unsigned int, r) >> 16);
}
// fp16 RTN split (for Q/K outputs): x = hi + lo to ~2^-22 rel
static __device__ __forceinline__ void splitf16(float x, unsigned short& hi, unsigned short& lo) {
    _Float16 h = (_Float16)x;
    hi = __builtin_bit_cast(unsigned short, h);
    _Float16 l = (_Float16)(x - (float)h);
    lo = __builtin_bit_cast(unsigned short, l);
}
// Q-row permutation: LDS row rho holds global q-row qperm(rho). Maps MFMA C-rows
// (lg*4+r) onto PV B-frag k-slots (lg*8+j) so P stays in registers.
static __device__ __forceinline__ int qperm(int r) {
    return ((r >> 5) << 5) | (((r >> 2) & 3) << 3) | (((r >> 4) & 1) << 2) | (r & 3);
}

// ---------------------------------------------------------------------------
// Pre-split the three weight matrices into bf16 hi/lo. grid (128, 3), 256 thr.
// ---------------------------------------------------------------------------
__global__ __launch_bounds__(256) void wsplit(
    const float* __restrict__ Wq, const float* __restrict__ Wk, const float* __restrict__ Wv,
    unsigned short* __restrict__ Whi, unsigned short* __restrict__ Wlo)
{
    const int z = blockIdx.y;
    const float* __restrict__ src = (z == 0) ? Wq : (z == 1) ? Wk : Wv;
    const int i = (blockIdx.x * 256 + threadIdx.x) * 8;
    float4 a = *(const float4*)&src[i];
    float4 b = *(const float4*)&src[i + 4];
    float v[8] = {a.x, a.y, a.z, a.w, b.x, b.y, b.z, b.w};
    unsigned short hb[8], lb[8];
    #pragma unroll
    for (int k = 0; k < 8; ++k) splitbf(v[k], hb[k], lb[k]);
    uint4 hv, lv;
    hv.x = (unsigned int)hb[0] | ((unsigned int)hb[1] << 16);
    hv.y = (unsigned int)hb[2] | ((unsigned int)hb[3] << 16);
    hv.z = (unsigned int)hb[4] | ((unsigned int)hb[5] << 16);
    hv.w = (unsigned int)hb[6] | ((unsigned int)hb[7] << 16);
    lv.x = (unsigned int)lb[0] | ((unsigned int)lb[1] << 16);
    lv.y = (unsigned int)lb[2] | ((unsigned int)lb[3] << 16);
    lv.z = (unsigned int)lb[4] | ((unsigned int)lb[5] << 16);
    lv.w = (unsigned int)lb[6] | ((unsigned int)lb[7] << 16);
    *(uint4*)&Whi[(size_t)z * WN + i] = hv;
    *(uint4*)&Wlo[(size_t)z * WN + i] = lv;
}

// ---------------------------------------------------------------------------
// Projection via 3-term split-bf16 MFMA. Y = X @ W^T + bias.
// grid (M/128, 512/64, 3), 256 thr (4 waves), BM=128 BN=64 BK=64.
//   z=0: Q -> fp16 (Qhi,Qlo), pre-scaled 0.125*log2(e) (base-2 softmax)
//   z=1: K -> fp16 (Khi,Klo)
//   z=2: V -> single fp16, transposed [b][h][d][T]
// ---------------------------------------------------------------------------
__global__ __launch_bounds__(256, 2) void proj_mfma(
    const float* __restrict__ X,
    const unsigned short* __restrict__ Whi, const unsigned short* __restrict__ Wlo,
    const float* __restrict__ bq, const float* __restrict__ bk, const float* __restrict__ bv,
    unsigned short* __restrict__ Qhi, unsigned short* __restrict__ Qlo,
    unsigned short* __restrict__ Khi, unsigned short* __restrict__ Klo,
    unsigned short* __restrict__ Vt)
{
    const int z = blockIdx.z;
    const int m0 = blockIdx.x * 128;
    const int n0 = blockIdx.y * 64;
    const int tid = threadIdx.x;
    const int wid = tid >> 6, lane = tid & 63;
    const int lg = lane >> 4, lr = lane & 15;

    __shared__ __attribute__((aligned(16))) unsigned short smem[384 * 72];
    auto Xh  = (unsigned short(*)[72])(smem);
    auto Xl  = (unsigned short(*)[72])(smem + 128 * 72);
    auto Wh2 = (unsigned short(*)[72])(smem + 256 * 72);
    auto Wl2 = (unsigned short(*)[72])(smem + 320 * 72);

    const unsigned short* __restrict__ Wh = Whi + (size_t)z * WN;
    const unsigned short* __restrict__ Wl = Wlo + (size_t)z * WN;

    f32x4 acc[2][4];
    #pragma unroll
    for (int rt = 0; rt < 2; ++rt)
        #pragma unroll
        for (int nt = 0; nt < 4; ++nt) acc[rt][nt] = (f32x4){0.f, 0.f, 0.f, 0.f};

    const int xr = tid >> 1;
    const int xc = (tid & 1) * 32;

    for (int k0 = 0; k0 < DM; k0 += 64) {
        #pragma unroll
        for (int w = 0; w < 4; ++w) {
            float4 fa = *(const float4*)&X[(size_t)(m0 + xr) * DM + k0 + xc + w * 8];
            float4 fb = *(const float4*)&X[(size_t)(m0 + xr) * DM + k0 + xc + w * 8 + 4];
            float v[8] = {fa.x, fa.y, fa.z, fa.w, fb.x, fb.y, fb.z, fb.w};
            unsigned short hb[8], lb[8];
            #pragma unroll
            for (int k = 0; k < 8; ++k) splitbf(v[k], hb[k], lb[k]);
            uint4 hv, lv;
            hv.x = (unsigned int)hb[0] | ((unsigned int)hb[1] << 16);
            hv.y = (unsigned int)hb[2] | ((unsigned int)hb[3] << 16);
            hv.z = (unsigned int)hb[4] | ((unsigned int)hb[5] << 16);
            hv.w = (unsigned int)hb[6] | ((unsigned int)hb[7] << 16);
            lv.x = (unsigned int)lb[0] | ((unsigned int)lb[1] << 16);
            lv.y = (unsigned int)lb[2] | ((unsigned int)lb[3] << 16);
            lv.z = (unsigned int)lb[4] | ((unsigned int)lb[5] << 16);
            lv.w = (unsigned int)lb[6] | ((unsigned int)lb[7] << 16);
            *(uint4*)&Xh[xr][xc + w * 8] = hv;
            *(uint4*)&Xl[xr][xc + w * 8] = lv;
        }
        #pragma unroll
        for (int it = 0; it < 2; ++it) {
            int i2 = it * 256 + tid;
            int fr = i2 >> 3, ch = i2 & 7;
            *(int4*)&Wh2[fr][ch * 8] = *(const int4*)&Wh[(size_t)(n0 + fr) * DM + k0 + ch * 8];
            *(int4*)&Wl2[fr][ch * 8] = *(const int4*)&Wl[(size_t)(n0 + fr) * DM + k0 + ch * 8];
        }
        __syncthreads();

        __builtin_amdgcn_s_setprio(1);
        #pragma unroll
        for (int kc = 0; kc < 2; ++kc) {
            short8 xa[2][2];
            #pragma unroll
            for (int rt = 0; rt < 2; ++rt) {
                xa[rt][0] = __builtin_bit_cast(short8, *(const int4*)&Xh[wid * 32 + rt * 16 + lr][kc * 32 + lg * 8]);
                xa[rt][1] = __builtin_bit_cast(short8, *(const int4*)&Xl[wid * 32 + rt * 16 + lr][kc * 32 + lg * 8]);
            }
            #pragma unroll
            for (int nt = 0; nt < 4; ++nt) {
                short8 wh = __builtin_bit_cast(short8, *(const int4*)&Wh2[nt * 16 + lr][kc * 32 + lg * 8]);
                short8 wl = __builtin_bit_cast(short8, *(const int4*)&Wl2[nt * 16 + lr][kc * 32 + lg * 8]);
                #pragma unroll
                for (int rt = 0; rt < 2; ++rt) {
                    acc[rt][nt] = __builtin_amdgcn_mfma_f32_16x16x32_bf16(xa[rt][0], wh, acc[rt][nt], 0, 0, 0);
                    acc[rt][nt] = __builtin_amdgcn_mfma_f32_16x16x32_bf16(xa[rt][1], wh, acc[rt][nt], 0, 0, 0);
                    acc[rt][nt] = __builtin_amdgcn_mfma_f32_16x16x32_bf16(xa[rt][0], wl, acc[rt][nt], 0, 0, 0);
                }
            }
        }
        __builtin_amdgcn_s_setprio(0);
        __syncthreads();
    }

    if (z < 2) {
        const float* __restrict__ bias = (z == 0) ? bq : bk;
        unsigned short* __restrict__ Hi = (z == 0) ? Qhi : Khi;
        unsigned short* __restrict__ Lo = (z == 0) ? Qlo : Klo;
        const float sc = (z == 0) ? 0.18033688f : 1.0f;   // 0.125 * log2(e)
        #pragma unroll
        for (int nt = 0; nt < 4; ++nt) {
            int n = n0 + nt * 16 + lr;
            float bv_ = bias[n];
            #pragma unroll
            for (int rt = 0; rt < 2; ++rt)
                #pragma unroll
                for (int r = 0; r < 4; ++r) {
                    int m = m0 + wid * 32 + rt * 16 + lg * 4 + r;
                    float y = (acc[rt][nt][r] + bv_) * sc;
                    unsigned short hb, lb;
                    splitf16(y, hb, lb);
                    Hi[(size_t)m * DM + n] = hb;
                    Lo[(size_t)m * DM + n] = lb;
                }
        }
    } else {
        // V: single fp16, bounce through LDS, write transposed [b][h][d][T]
        unsigned short* Tk = (unsigned short*)smem;   // [64][136]
        #pragma unroll
        for (int nt = 0; nt < 4; ++nt) {
            int d = nt * 16 + lr;
            float bv_ = bv[n0 + d];
            #pragma unroll
            for (int rt = 0; rt < 2; ++rt)
                #pragma unroll
                for (int r = 0; r < 4; ++r) {
                    int t = wid * 32 + rt * 16 + lg * 4 + r;
                    float y = acc[rt][nt][r] + bv_;
                    Tk[d * 136 + t] = __builtin_bit_cast(unsigned short, (_Float16)y);
                }
        }
        __syncthreads();
        const int dl = tid >> 2, tq = tid & 3;
        const int bb = m0 >> 12, t0 = m0 & (TT - 1), h = n0 >> 6;
        size_t obase = ((size_t)((bb * NH + h) * HD + dl)) * TT + t0 + tq * 32;
        unsigned int w[16];
        #pragma unroll
        for (int k = 0; k < 16; ++k)
            w[k] = (unsigned int)Tk[dl * 136 + tq * 32 + 2 * k]
                 | ((unsigned int)Tk[dl * 136 + tq * 32 + 2 * k + 1] << 16);
        #pragma unroll
        for (int j = 0; j < 4; ++j) {
            uint4 wv = {w[4 * j], w[4 * j + 1], w[4 * j + 2], w[4 * j + 3]};
            *(uint4*)&Vt[obase + j * 8] = wv;
        }
    }
}

// ---------------------------------------------------------------------------
// Flash attention, fp16, DOUBLE-BUFFERED pipeline (T3/T4-lite): issue next
// tile's global_load_lds into buf^1, counted s_waitcnt vmcnt(6) (never 0 in
// steady state), raw s_barrier. Base-2 softmax (Q pre-scaled by log2e/8),
// defer-max (skip rescale when max growth <= 4 ulp2). 32 krows/wave,
// 128/block, grid 512 = 2 blocks/CU (48KB LDS dbuf).
// ---------------------------------------------------------------------------
__global__ __launch_bounds__(256, 2) void attn_mfma(
    const unsigned short* __restrict__ Qhi, const unsigned short* __restrict__ Qlo,
    const unsigned short* __restrict__ Khi, const unsigned short* __restrict__ Klo,
    const unsigned short* __restrict__ Vt,
    float* __restrict__ Out)
{
    const int flat = blockIdx.x;
    const int bh = flat & 15;                 // XCD-grouping: same bh -> same XCD
    const int r0 = (flat >> 4) * 128;
    const int b = bh >> 3, h = bh & 7;
    const int tid = threadIdx.x;
    const int wid = tid >> 6, lane = tid & 63;
    const int lg = lane >> 4, lr = lane & 15;
    const int wr0 = r0 + wid * 32;

    __shared__ __attribute__((aligned(16))) unsigned short Qs[2][128][64];
    __shared__ __attribute__((aligned(16))) unsigned short Vs[2][64][64];

    const size_t qbase = (size_t)b * TT * DM + h * HD;
    const size_t vbase = ((size_t)(b * NH + h)) * HD * TT;

    // K fragments resident in registers: [rowtile][kc][hi/lo]
    half8 kf[2][2][2];
    #pragma unroll
    for (int rt = 0; rt < 2; ++rt)
        #pragma unroll
        for (int kc = 0; kc < 2; ++kc) {
            size_t g = qbase + (size_t)(wr0 + rt * 16 + lr) * DM + kc * 32 + lg * 8;
            kf[rt][kc][0] = __builtin_bit_cast(half8, *(const int4*)&Khi[g]);
            kf[rt][kc][1] = __builtin_bit_cast(half8, *(const int4*)&Klo[g]);
        }

    // stage one tile (6 GLD16/thread) into buffer bufi
    auto stage = [&](int c0, int bufi) {
        #pragma unroll
        for (int it = 0; it < 4; ++it) {
            int gi = it * 256 + tid;
            int fr = gi >> 3;
            int ch = (gi & 7) ^ (fr & 7);
            const unsigned short* qsrc = (fr < 64) ? Qhi : Qlo;
            GLD16(&qsrc[qbase + (size_t)(c0 + qperm(fr & 63)) * DM + ch * 8],
                  (char*)&Qs[bufi][0][0] + (it * 256 + wid * 64) * 16);
        }
        #pragma unroll
        for (int it = 0; it < 2; ++it) {
            int gi = it * 256 + tid;
            int fr = gi >> 3;
            int ch = (gi & 7) ^ (fr & 7);
            GLD16(&Vt[vbase + (size_t)fr * TT + c0 + ch * 8],
                  (char*)&Vs[bufi][0][0] + (it * 256 + wid * 64) * 16);
        }
    };

    float m_s[2], l_s[2];
    f32x4 oacc[2][4];
    #pragma unroll
    for (int rt = 0; rt < 2; ++rt) {
        m_s[rt] = -INFINITY; l_s[rt] = 0.f;
        #pragma unroll
        for (int dt = 0; dt < 4; ++dt) oacc[rt][dt] = (f32x4){0.f, 0.f, 0.f, 0.f};
    }

    stage(0, 0);   // prologue: tile 0 -> buf 0

    for (int t = 0; t < TT / 64; ++t) {
        const int cur = t & 1;
        if (t < TT / 64 - 1) {
            stage((t + 1) * 64, cur ^ 1);
            __builtin_amdgcn_sched_barrier(0);
            asm volatile("s_waitcnt vmcnt(6)" ::: "memory");   // tile-t done; t+1 in flight
        } else {
            __builtin_amdgcn_sched_barrier(0);
            asm volatile("s_waitcnt vmcnt(0)" ::: "memory");
        }
        __builtin_amdgcn_sched_barrier(0);
        __builtin_amdgcn_s_barrier();
        __builtin_amdgcn_sched_barrier(0);

        // ---- S^T = Q @ K^T, 3-term fp16 split (scores in log2 domain)
        f32x4 sacc[2][4];
        #pragma unroll
        for (int rt = 0; rt < 2; ++rt)
            #pragma unroll
            for (int qt = 0; qt < 4; ++qt) sacc[rt][qt] = (f32x4){0.f, 0.f, 0.f, 0.f};
        __builtin_amdgcn_s_setprio(1);
        #pragma unroll
        for (int kc = 0; kc < 2; ++kc) {
            #pragma unroll
            for (int qt = 0; qt < 4; ++qt) {
                int row = qt * 16 + lr;
                int so = ((kc * 4 + lg) ^ (row & 7)) * 16;
                half8 qh = __builtin_bit_cast(half8, *(const int4*)((const char*)&Qs[cur][row][0] + so));
                half8 ql = __builtin_bit_cast(half8, *(const int4*)((const char*)&Qs[cur][64 + row][0] + so));
                #pragma unroll
                for (int rt = 0; rt < 2; ++rt) {
                    sacc[rt][qt] = __builtin_amdgcn_mfma_f32_16x16x32_f16(qh, kf[rt][kc][0], sacc[rt][qt], 0, 0, 0);
                    sacc[rt][qt] = __builtin_amdgcn_mfma_f32_16x16x32_f16(ql, kf[rt][kc][0], sacc[rt][qt], 0, 0, 0);
                    sacc[rt][qt] = __builtin_amdgcn_mfma_f32_16x16x32_f16(qh, kf[rt][kc][1], sacc[rt][qt], 0, 0, 0);
                }
            }
        }
        __builtin_amdgcn_s_setprio(0);

        // ---- online softmax, base-2, defer-max; p' = 2^(s - m + 11)
        unsigned int hp[2][4][2];
        #pragma unroll
        for (int rt = 0; rt < 2; ++rt) {
            float mx = -INFINITY;
            #pragma unroll
            for (int qt = 0; qt < 4; ++qt)
                #pragma unroll
                for (int r = 0; r < 4; ++r) mx = fmaxf(mx, sacc[rt][qt][r]);
            mx = fmaxf(mx, __shfl_xor(mx, 16));
            mx = fmaxf(mx, __shfl_xor(mx, 32));
            if (!__all(mx - m_s[rt] <= 4.0f)) {           // rescale path (rare)
                float nm = fmaxf(m_s[rt], mx);
                float al = exp2f(m_s[rt] - nm);
                l_s[rt] *= al;
                #pragma unroll
                for (int dt = 0; dt < 4; ++dt)
                    #pragma unroll
                    for (int r = 0; r < 4; ++r) oacc[rt][dt][r] *= al;
                m_s[rt] = nm;
            }
            const float nmb = m_s[rt] - 11.0f;            // p' = 2^(s-m+11) <= 2^15
            float sum = 0.f;
            #pragma unroll
            for (int qt = 0; qt < 4; ++qt)
                #pragma unroll
                for (int r = 0; r < 4; ++r) {
                    float p = exp2f(sacc[rt][qt][r] - nmb);
                    sacc[rt][qt][r] = p;
                    sum += p;
                }
            sum += __shfl_xor(sum, 16);
            sum += __shfl_xor(sum, 32);
            l_s[rt] += sum;
            #pragma unroll
            for (int qt = 0; qt < 4; ++qt)
                #pragma unroll
                for (int pp = 0; pp < 2; ++pp)
                    hp[rt][qt][pp] = __builtin_bit_cast(unsigned int,
                        __builtin_amdgcn_cvt_pkrtz(sacc[rt][qt][2 * pp], sacc[rt][qt][2 * pp + 1]));
        }

        // ---- out^T += V^T @ P, single fp16 term
        __builtin_amdgcn_s_setprio(1);
        #pragma unroll
        for (int c = 0; c < 2; ++c) {
            half8 pf[2];
            #pragma unroll
            for (int rt = 0; rt < 2; ++rt) {
                int4 ph4 = {(int)hp[rt][2 * c][0], (int)hp[rt][2 * c][1],
                            (int)hp[rt][2 * c + 1][0], (int)hp[rt][2 * c + 1][1]};
                pf[rt] = __builtin_bit_cast(half8, ph4);
            }
            #pragma unroll
            for (int dt = 0; dt < 4; ++dt) {
                int row = dt * 16 + lr;
                int so = ((c * 4 + lg) ^ (row & 7)) * 16;
                half8 vh = __builtin_bit_cast(half8, *(const int4*)((const char*)&Vs[cur][row][0] + so));
                #pragma unroll
                for (int rt = 0; rt < 2; ++rt)
                    oacc[rt][dt] = __builtin_amdgcn_mfma_f32_16x16x32_f16(vh, pf[rt], oacc[rt][dt], 0, 0, 0);
            }
        }
        __builtin_amdgcn_s_setprio(0);
        __builtin_amdgcn_sched_barrier(0);
        asm volatile("" ::: "memory");
        __builtin_amdgcn_s_barrier();       // all waves done reading buf[cur]
        __builtin_amdgcn_sched_barrier(0);
    }

    // epilogue: out[krow][d] = oacc / l  (2^11 scale cancels)
    #pragma unroll
    for (int rt = 0; rt < 2; ++rt) {
        float inv = __builtin_amdgcn_rcpf(l_s[rt]);
        int row = wr0 + rt * 16 + lr;
        #pragma unroll
        for (int dt = 0; dt < 4; ++dt)
            #pragma unroll
            for (int r = 0; r < 4; ++r)
                Out[((size_t)(b * TT + row)) * DM + h * HD + dt * 16 + lg * 4 + r] =
                    oacc[rt][dt][r] * inv;
    }
}

// ---------------------------------------------------------------------------
extern "C" void kernel_launch(void* const* d_in, const int* in_sizes, int n_in,
                              void* d_out, int out_size, void* d_ws, size_t ws_size,
                              hipStream_t stream)
{
    const float* x  = (const float*)d_in[0];
    const float* Wk = (const float*)d_in[1];
    const float* bk = (const float*)d_in[2];
    const float* Wq = (const float*)d_in[3];
    const float* bq = (const float*)d_in[4];
    const float* Wv = (const float*)d_in[5];
    const float* bv = (const float*)d_in[6];
    float* out = (float*)d_out;

    const size_t SZ = (size_t)2 * TT * DM;
    unsigned short* Qhi = (unsigned short*)d_ws;
    unsigned short* Qlo = Qhi + SZ;
    unsigned short* Khi = Qlo + SZ;
    unsigned short* Klo = Khi + SZ;
    unsigned short* Vt  = Klo + SZ;
    unsigned short* Whi = Vt + SZ;
    unsigned short* Wlo = Whi + (size_t)3 * WN;

    wsplit<<<dim3(WN / 2048, 3), dim3(256), 0, stream>>>(Wq, Wk, Wv, Whi, Wlo);

    dim3 pgrid(2 * TT / 128, DM / 64, 3);
    proj_mfma<<<pgrid, dim3(256), 0, stream>>>(x, Whi, Wlo, bq, bk, bv,
                                               Qhi, Qlo, Khi, Klo, Vt);

    attn_mfma<<<dim3(512), dim3(256), 0, stream>>>(Qhi, Qlo, Khi, Klo, Vt, out);
}

// Round 10
// 218.849 us; speedup vs baseline: 1.0796x; 1.0590x over previous
//
#include <hip/hip_runtime.h>
#include <math.h>

#define TT 4096
#define DM 512
#define NH 8
#define HD 64
#define WN (DM * DM)   // 262144 elements per weight matrix

typedef float f32x4 __attribute__((ext_vector_type(4)));
typedef short short8 __attribute__((ext_vector_type(8)));
typedef _Float16 half8 __attribute__((ext_vector_type(8)));

#define GLD16(gp, lp) __builtin_amdgcn_global_load_lds( \
    (const __attribute__((address_space(1))) void*)(gp), \
    (__attribute__((address_space(3))) void*)(lp), 16, 0, 0)

static __device__ __forceinline__ float bf2f(unsigned short h) {
    unsigned int u = ((unsigned int)h) << 16;
    return __builtin_bit_cast(float, u);
}
// bf16 truncation split (for proj X/W staging)
static __device__ __forceinline__ void splitbf(float x, unsigned short& hi, unsigned short& lo) {
    unsigned int u = __builtin_bit_cast(unsigned int, x);
    hi = (unsigned short)(u >> 16);
    float r = x - bf2f(hi);
    lo = (unsigned short)(__builtin_bit_cast(unsigned int, r) >> 16);
}
// fp16 RTN split (for Q/K outputs): x = hi + lo to ~2^-22 rel
static __device__ __forceinline__ void splitf16(float x, unsigned short& hi, unsigned short& lo) {
    _Float16 h = (_Float16)x;
    hi = __builtin_bit_cast(unsigned short, h);
    _Float16 l = (_Float16)(x - (float)h);
    lo = __builtin_bit_cast(unsigned short, l);
}
// Q-row permutation: LDS row rho holds global q-row qperm(rho). Maps MFMA C-rows
// (lg*4+r) onto PV B-frag k-slots (lg*8+j) so P stays in registers.
static __device__ __forceinline__ int qperm(int r) {
    return ((r >> 5) << 5) | (((r >> 2) & 3) << 3) | (((r >> 4) & 1) << 2) | (r & 3);
}

// ---------------------------------------------------------------------------
// Pre-split the three weight matrices into bf16 hi/lo. grid (128, 3), 256 thr.
// ---------------------------------------------------------------------------
__global__ __launch_bounds__(256) void wsplit(
    const float* __restrict__ Wq, const float* __restrict__ Wk, const float* __restrict__ Wv,
    unsigned short* __restrict__ Whi, unsigned short* __restrict__ Wlo)
{
    const int z = blockIdx.y;
    const float* __restrict__ src = (z == 0) ? Wq : (z == 1) ? Wk : Wv;
    const int i = (blockIdx.x * 256 + threadIdx.x) * 8;
    float4 a = *(const float4*)&src[i];
    float4 b = *(const float4*)&src[i + 4];
    float v[8] = {a.x, a.y, a.z, a.w, b.x, b.y, b.z, b.w};
    unsigned short hb[8], lb[8];
    #pragma unroll
    for (int k = 0; k < 8; ++k) splitbf(v[k], hb[k], lb[k]);
    uint4 hv, lv;
    hv.x = (unsigned int)hb[0] | ((unsigned int)hb[1] << 16);
    hv.y = (unsigned int)hb[2] | ((unsigned int)hb[3] << 16);
    hv.z = (unsigned int)hb[4] | ((unsigned int)hb[5] << 16);
    hv.w = (unsigned int)hb[6] | ((unsigned int)hb[7] << 16);
    lv.x = (unsigned int)lb[0] | ((unsigned int)lb[1] << 16);
    lv.y = (unsigned int)lb[2] | ((unsigned int)lb[3] << 16);
    lv.z = (unsigned int)lb[4] | ((unsigned int)lb[5] << 16);
    lv.w = (unsigned int)lb[6] | ((unsigned int)lb[7] << 16);
    *(uint4*)&Whi[(size_t)z * WN + i] = hv;
    *(uint4*)&Wlo[(size_t)z * WN + i] = lv;
}

// ---------------------------------------------------------------------------
// Projection via 3-term split-bf16 MFMA. Y = X @ W^T + bias.
// grid (M/128, 512/64, 3), 256 thr (4 waves), BM=128 BN=64 BK=64.
//   z=0: Q -> fp16 (Qhi,Qlo), pre-scaled 0.125
//   z=1: K -> fp16 (Khi,Klo)
//   z=2: V -> single fp16, transposed [b][h][d][T]
// ---------------------------------------------------------------------------
__global__ __launch_bounds__(256, 2) void proj_mfma(
    const float* __restrict__ X,
    const unsigned short* __restrict__ Whi, const unsigned short* __restrict__ Wlo,
    const float* __restrict__ bq, const float* __restrict__ bk, const float* __restrict__ bv,
    unsigned short* __restrict__ Qhi, unsigned short* __restrict__ Qlo,
    unsigned short* __restrict__ Khi, unsigned short* __restrict__ Klo,
    unsigned short* __restrict__ Vt)
{
    const int z = blockIdx.z;
    const int m0 = blockIdx.x * 128;
    const int n0 = blockIdx.y * 64;
    const int tid = threadIdx.x;
    const int wid = tid >> 6, lane = tid & 63;
    const int lg = lane >> 4, lr = lane & 15;

    __shared__ __attribute__((aligned(16))) unsigned short smem[384 * 72];
    auto Xh  = (unsigned short(*)[72])(smem);
    auto Xl  = (unsigned short(*)[72])(smem + 128 * 72);
    auto Wh2 = (unsigned short(*)[72])(smem + 256 * 72);
    auto Wl2 = (unsigned short(*)[72])(smem + 320 * 72);

    const unsigned short* __restrict__ Wh = Whi + (size_t)z * WN;
    const unsigned short* __restrict__ Wl = Wlo + (size_t)z * WN;

    f32x4 acc[2][4];
    #pragma unroll
    for (int rt = 0; rt < 2; ++rt)
        #pragma unroll
        for (int nt = 0; nt < 4; ++nt) acc[rt][nt] = (f32x4){0.f, 0.f, 0.f, 0.f};

    const int xr = tid >> 1;
    const int xc = (tid & 1) * 32;

    for (int k0 = 0; k0 < DM; k0 += 64) {
        #pragma unroll
        for (int w = 0; w < 4; ++w) {
            float4 fa = *(const float4*)&X[(size_t)(m0 + xr) * DM + k0 + xc + w * 8];
            float4 fb = *(const float4*)&X[(size_t)(m0 + xr) * DM + k0 + xc + w * 8 + 4];
            float v[8] = {fa.x, fa.y, fa.z, fa.w, fb.x, fb.y, fb.z, fb.w};
            unsigned short hb[8], lb[8];
            #pragma unroll
            for (int k = 0; k < 8; ++k) splitbf(v[k], hb[k], lb[k]);
            uint4 hv, lv;
            hv.x = (unsigned int)hb[0] | ((unsigned int)hb[1] << 16);
            hv.y = (unsigned int)hb[2] | ((unsigned int)hb[3] << 16);
            hv.z = (unsigned int)hb[4] | ((unsigned int)hb[5] << 16);
            hv.w = (unsigned int)hb[6] | ((unsigned int)hb[7] << 16);
            lv.x = (unsigned int)lb[0] | ((unsigned int)lb[1] << 16);
            lv.y = (unsigned int)lb[2] | ((unsigned int)lb[3] << 16);
            lv.z = (unsigned int)lb[4] | ((unsigned int)lb[5] << 16);
            lv.w = (unsigned int)lb[6] | ((unsigned int)lb[7] << 16);
            *(uint4*)&Xh[xr][xc + w * 8] = hv;
            *(uint4*)&Xl[xr][xc + w * 8] = lv;
        }
        #pragma unroll
        for (int it = 0; it < 2; ++it) {
            int i2 = it * 256 + tid;
            int fr = i2 >> 3, ch = i2 & 7;
            *(int4*)&Wh2[fr][ch * 8] = *(const int4*)&Wh[(size_t)(n0 + fr) * DM + k0 + ch * 8];
            *(int4*)&Wl2[fr][ch * 8] = *(const int4*)&Wl[(size_t)(n0 + fr) * DM + k0 + ch * 8];
        }
        __syncthreads();

        __builtin_amdgcn_s_setprio(1);
        #pragma unroll
        for (int kc = 0; kc < 2; ++kc) {
            short8 xa[2][2];
            #pragma unroll
            for (int rt = 0; rt < 2; ++rt) {
                xa[rt][0] = __builtin_bit_cast(short8, *(const int4*)&Xh[wid * 32 + rt * 16 + lr][kc * 32 + lg * 8]);
                xa[rt][1] = __builtin_bit_cast(short8, *(const int4*)&Xl[wid * 32 + rt * 16 + lr][kc * 32 + lg * 8]);
            }
            #pragma unroll
            for (int nt = 0; nt < 4; ++nt) {
                short8 wh = __builtin_bit_cast(short8, *(const int4*)&Wh2[nt * 16 + lr][kc * 32 + lg * 8]);
                short8 wl = __builtin_bit_cast(short8, *(const int4*)&Wl2[nt * 16 + lr][kc * 32 + lg * 8]);
                #pragma unroll
                for (int rt = 0; rt < 2; ++rt) {
                    acc[rt][nt] = __builtin_amdgcn_mfma_f32_16x16x32_bf16(xa[rt][0], wh, acc[rt][nt], 0, 0, 0);
                    acc[rt][nt] = __builtin_amdgcn_mfma_f32_16x16x32_bf16(xa[rt][1], wh, acc[rt][nt], 0, 0, 0);
                    acc[rt][nt] = __builtin_amdgcn_mfma_f32_16x16x32_bf16(xa[rt][0], wl, acc[rt][nt], 0, 0, 0);
                }
            }
        }
        __builtin_amdgcn_s_setprio(0);
        __syncthreads();
    }

    if (z < 2) {
        const float* __restrict__ bias = (z == 0) ? bq : bk;
        unsigned short* __restrict__ Hi = (z == 0) ? Qhi : Khi;
        unsigned short* __restrict__ Lo = (z == 0) ? Qlo : Klo;
        const float sc = (z == 0) ? 0.125f : 1.0f;
        #pragma unroll
        for (int nt = 0; nt < 4; ++nt) {
            int n = n0 + nt * 16 + lr;
            float bv_ = bias[n];
            #pragma unroll
            for (int rt = 0; rt < 2; ++rt)
                #pragma unroll
                for (int r = 0; r < 4; ++r) {
                    int m = m0 + wid * 32 + rt * 16 + lg * 4 + r;
                    float y = (acc[rt][nt][r] + bv_) * sc;
                    unsigned short hb, lb;
                    splitf16(y, hb, lb);
                    Hi[(size_t)m * DM + n] = hb;
                    Lo[(size_t)m * DM + n] = lb;
                }
        }
    } else {
        // V: single fp16, bounce through LDS, write transposed [b][h][d][T]
        unsigned short* Tk = (unsigned short*)smem;   // [64][136]
        #pragma unroll
        for (int nt = 0; nt < 4; ++nt) {
            int d = nt * 16 + lr;
            float bv_ = bv[n0 + d];
            #pragma unroll
            for (int rt = 0; rt < 2; ++rt)
                #pragma unroll
                for (int r = 0; r < 4; ++r) {
                    int t = wid * 32 + rt * 16 + lg * 4 + r;
                    float y = acc[rt][nt][r] + bv_;
                    Tk[d * 136 + t] = __builtin_bit_cast(unsigned short, (_Float16)y);
                }
        }
        __syncthreads();
        const int dl = tid >> 2, tq = tid & 3;
        const int bb = m0 >> 12, t0 = m0 & (TT - 1), h = n0 >> 6;
        size_t obase = ((size_t)((bb * NH + h) * HD + dl)) * TT + t0 + tq * 32;
        unsigned int w[16];
        #pragma unroll
        for (int k = 0; k < 16; ++k)
            w[k] = (unsigned int)Tk[dl * 136 + tq * 32 + 2 * k]
                 | ((unsigned int)Tk[dl * 136 + tq * 32 + 2 * k + 1] << 16);
        #pragma unroll
        for (int j = 0; j < 4; ++j) {
            uint4 wv = {w[4 * j], w[4 * j + 1], w[4 * j + 2], w[4 * j + 3]};
            *(uint4*)&Vt[obase + j * 8] = wv;
        }
    }
}

// ---------------------------------------------------------------------------
// Flash attention, fp16 (round-7 numerics). 128-q steps staged as TWO 64-q
// sub-buffers; two compute passes share one barrier pair (passes only read
// LDS). Staging addresses hoisted to persistent pointers (+const per step).
// 32 krows/wave, 128 krows/block, grid 512. LDS 48KB, 2 blocks/CU.
// ---------------------------------------------------------------------------
__global__ __launch_bounds__(256, 2) void attn_mfma(
    const unsigned short* __restrict__ Qhi, const unsigned short* __restrict__ Qlo,
    const unsigned short* __restrict__ Khi, const unsigned short* __restrict__ Klo,
    const unsigned short* __restrict__ Vt,
    float* __restrict__ Out)
{
    const int flat = blockIdx.x;
    const int bh = flat & 15;                 // XCD-grouping: same bh -> same XCD
    const int r0 = (flat >> 4) * 128;
    const int b = bh >> 3, h = bh & 7;
    const int tid = threadIdx.x;
    const int wid = tid >> 6, lane = tid & 63;
    const int lg = lane >> 4, lr = lane & 15;
    const int wr0 = r0 + wid * 32;

    __shared__ __attribute__((aligned(16))) unsigned short Qs[2][128][64]; // [pass][hi 0-63 | lo 64-127][d]
    __shared__ __attribute__((aligned(16))) unsigned short Vs[2][64][64];  // [pass][d][q]

    const size_t qbase = (size_t)b * TT * DM + h * HD;
    const size_t vbase = ((size_t)(b * NH + h)) * HD * TT;

    // K fragments resident in registers: [rowtile][kc][hi/lo]
    half8 kf[2][2][2];
    #pragma unroll
    for (int rt = 0; rt < 2; ++rt)
        #pragma unroll
        for (int kc = 0; kc < 2; ++kc) {
            size_t g = qbase + (size_t)(wr0 + rt * 16 + lr) * DM + kc * 32 + lg * 8;
            kf[rt][kc][0] = __builtin_bit_cast(half8, *(const int4*)&Khi[g]);
            kf[rt][kc][1] = __builtin_bit_cast(half8, *(const int4*)&Klo[g]);
        }

    // hoisted staging pointers (advance by constant per 128-q step)
    const unsigned short* qp[4];
    const unsigned short* vp[2];
    int qlds[4], vlds[2];
    #pragma unroll
    for (int it = 0; it < 4; ++it) {
        int gi = it * 256 + tid;
        int fr = gi >> 3;
        int ch = (gi & 7) ^ (fr & 7);
        qp[it] = ((fr < 64) ? Qhi : Qlo) + qbase + (size_t)qperm(fr & 63) * DM + ch * 8;
        qlds[it] = (it * 256 + wid * 64) * 16;
    }
    #pragma unroll
    for (int it = 0; it < 2; ++it) {
        int gi = it * 256 + tid;
        int fr = gi >> 3;
        int ch = (gi & 7) ^ (fr & 7);
        vp[it] = Vt + vbase + (size_t)fr * TT + ch * 8;
        vlds[it] = (it * 256 + wid * 64) * 16;
    }

    float m_s[2], l_s[2];
    f32x4 oacc[2][4];
    #pragma unroll
    for (int rt = 0; rt < 2; ++rt) {
        m_s[rt] = -INFINITY; l_s[rt] = 0.f;
        #pragma unroll
        for (int dt = 0; dt < 4; ++dt) oacc[rt][dt] = (f32x4){0.f, 0.f, 0.f, 0.f};
    }

    for (int t = 0; t < TT / 128; ++t) {
        // ---- stage both 64-q sub-tiles (12 GLD16/thread), hoisted pointers
        #pragma unroll
        for (int tau = 0; tau < 2; ++tau) {
            #pragma unroll
            for (int it = 0; it < 4; ++it)
                GLD16(qp[it] + (size_t)tau * 64 * DM, (char*)&Qs[tau][0][0] + qlds[it]);
            #pragma unroll
            for (int it = 0; it < 2; ++it)
                GLD16(vp[it] + tau * 64, (char*)&Vs[tau][0][0] + vlds[it]);
        }
        #pragma unroll
        for (int it = 0; it < 4; ++it) qp[it] += 128 * DM;
        #pragma unroll
        for (int it = 0; it < 2; ++it) vp[it] += 128;
        __syncthreads();

        // ---- two compute passes, no barrier between (read-only LDS)
        #pragma unroll
        for (int tau = 0; tau < 2; ++tau) {
            // S^T = Q @ K^T, 3-term fp16 split
            f32x4 sacc[2][4];
            #pragma unroll
            for (int rt = 0; rt < 2; ++rt)
                #pragma unroll
                for (int qt = 0; qt < 4; ++qt) sacc[rt][qt] = (f32x4){0.f, 0.f, 0.f, 0.f};
            __builtin_amdgcn_s_setprio(1);
            #pragma unroll
            for (int kc = 0; kc < 2; ++kc) {
                #pragma unroll
                for (int qt = 0; qt < 4; ++qt) {
                    int row = qt * 16 + lr;
                    int so = ((kc * 4 + lg) ^ (row & 7)) * 16;
                    half8 qh = __builtin_bit_cast(half8, *(const int4*)((const char*)&Qs[tau][row][0] + so));
                    half8 ql = __builtin_bit_cast(half8, *(const int4*)((const char*)&Qs[tau][64 + row][0] + so));
                    #pragma unroll
                    for (int rt = 0; rt < 2; ++rt) {
                        sacc[rt][qt] = __builtin_amdgcn_mfma_f32_16x16x32_f16(qh, kf[rt][kc][0], sacc[rt][qt], 0, 0, 0);
                        sacc[rt][qt] = __builtin_amdgcn_mfma_f32_16x16x32_f16(ql, kf[rt][kc][0], sacc[rt][qt], 0, 0, 0);
                        sacc[rt][qt] = __builtin_amdgcn_mfma_f32_16x16x32_f16(qh, kf[rt][kc][1], sacc[rt][qt], 0, 0, 0);
                    }
                }
            }
            __builtin_amdgcn_s_setprio(0);

            // online softmax per krow + fp16 pack, scaled e^7.62
            unsigned int hp[2][4][2];
            #pragma unroll
            for (int rt = 0; rt < 2; ++rt) {
                float mx = -INFINITY;
                #pragma unroll
                for (int qt = 0; qt < 4; ++qt)
                    #pragma unroll
                    for (int r = 0; r < 4; ++r) mx = fmaxf(mx, sacc[rt][qt][r]);
                mx = fmaxf(mx, __shfl_xor(mx, 16));
                mx = fmaxf(mx, __shfl_xor(mx, 32));
                float nm = fmaxf(m_s[rt], mx);
                float al = __expf(m_s[rt] - nm);
                const float nmb = nm - 7.6246190f;       // ln(2048): p' = 2048*p
                float sum = 0.f;
                #pragma unroll
                for (int qt = 0; qt < 4; ++qt)
                    #pragma unroll
                    for (int r = 0; r < 4; ++r) {
                        float p = __expf(sacc[rt][qt][r] - nmb);
                        sacc[rt][qt][r] = p;
                        sum += p;
                    }
                sum += __shfl_xor(sum, 16);
                sum += __shfl_xor(sum, 32);
                m_s[rt] = nm;
                l_s[rt] = l_s[rt] * al + sum;
                #pragma unroll
                for (int qt = 0; qt < 4; ++qt)
                    #pragma unroll
                    for (int pp = 0; pp < 2; ++pp)
                        hp[rt][qt][pp] = __builtin_bit_cast(unsigned int,
                            __builtin_amdgcn_cvt_pkrtz(sacc[rt][qt][2 * pp], sacc[rt][qt][2 * pp + 1]));
                #pragma unroll
                for (int dt = 0; dt < 4; ++dt)
                    #pragma unroll
                    for (int r = 0; r < 4; ++r) oacc[rt][dt][r] *= al;
            }

            // out^T += V^T @ P, single fp16 term
            __builtin_amdgcn_s_setprio(1);
            #pragma unroll
            for (int c = 0; c < 2; ++c) {
                half8 pf[2];
                #pragma unroll
                for (int rt = 0; rt < 2; ++rt) {
                    int4 ph4 = {(int)hp[rt][2 * c][0], (int)hp[rt][2 * c][1],
                                (int)hp[rt][2 * c + 1][0], (int)hp[rt][2 * c + 1][1]};
                    pf[rt] = __builtin_bit_cast(half8, ph4);
                }
                #pragma unroll
                for (int dt = 0; dt < 4; ++dt) {
                    int row = dt * 16 + lr;
                    int so = ((c * 4 + lg) ^ (row & 7)) * 16;
                    half8 vh = __builtin_bit_cast(half8, *(const int4*)((const char*)&Vs[tau][row][0] + so));
                    #pragma unroll
                    for (int rt = 0; rt < 2; ++rt)
                        oacc[rt][dt] = __builtin_amdgcn_mfma_f32_16x16x32_f16(vh, pf[rt], oacc[rt][dt], 0, 0, 0);
                }
            }
            __builtin_amdgcn_s_setprio(0);
        }
        __syncthreads();
    }

    // epilogue: out[krow][d] = oacc / l  (scale 2048 cancels)
    #pragma unroll
    for (int rt = 0; rt < 2; ++rt) {
        float inv = __builtin_amdgcn_rcpf(l_s[rt]);
        int row = wr0 + rt * 16 + lr;
        #pragma unroll
        for (int dt = 0; dt < 4; ++dt)
            #pragma unroll
            for (int r = 0; r < 4; ++r)
                Out[((size_t)(b * TT + row)) * DM + h * HD + dt * 16 + lg * 4 + r] =
                    oacc[rt][dt][r] * inv;
    }
}

// ---------------------------------------------------------------------------
extern "C" void kernel_launch(void* const* d_in, const int* in_sizes, int n_in,
                              void* d_out, int out_size, void* d_ws, size_t ws_size,
                              hipStream_t stream)
{
    const float* x  = (const float*)d_in[0];
    const float* Wk = (const float*)d_in[1];
    const float* bk = (const float*)d_in[2];
    const float* Wq = (const float*)d_in[3];
    const float* bq = (const float*)d_in[4];
    const float* Wv = (const float*)d_in[5];
    const float* bv = (const float*)d_in[6];
    float* out = (float*)d_out;

    const size_t SZ = (size_t)2 * TT * DM;
    unsigned short* Qhi = (unsigned short*)d_ws;
    unsigned short* Qlo = Qhi + SZ;
    unsigned short* Khi = Qlo + SZ;
    unsigned short* Klo = Khi + SZ;
    unsigned short* Vt  = Klo + SZ;
    unsigned short* Whi = Vt + SZ;
    unsigned short* Wlo = Whi + (size_t)3 * WN;

    wsplit<<<dim3(WN / 2048, 3), dim3(256), 0, stream>>>(Wq, Wk, Wv, Whi, Wlo);

    dim3 pgrid(2 * TT / 128, DM / 64, 3);
    proj_mfma<<<pgrid, dim3(256), 0, stream>>>(x, Whi, Wlo, bq, bk, bv,
                                               Qhi, Qlo, Khi, Klo, Vt);

    attn_mfma<<<dim3(512), dim3(256), 0, stream>>>(Qhi, Qlo, Khi, Klo, Vt, out);
}

// Round 11
// 196.082 us; speedup vs baseline: 1.2049x; 1.1161x over previous
//
#include <hip/hip_runtime.h>
#include <math.h>

#define TT 4096
#define DM 512
#define NH 8
#define HD 64
#define WN (DM * DM)   // 262144 elements per weight matrix

typedef float f32x4 __attribute__((ext_vector_type(4)));
typedef short short8 __attribute__((ext_vector_type(8)));
typedef _Float16 half8 __attribute__((ext_vector_type(8)));

#define GLD16(gp, lp) __builtin_amdgcn_global_load_lds( \
    (const __attribute__((address_space(1))) void*)(gp), \
    (__attribute__((address_space(3))) void*)(lp), 16, 0, 0)

static __device__ __forceinline__ float bf2f(unsigned short h) {
    unsigned int u = ((unsigned int)h) << 16;
    return __builtin_bit_cast(float, u);
}
// bf16 truncation split (for proj X/W staging)
static __device__ __forceinline__ void splitbf(float x, unsigned short& hi, unsigned short& lo) {
    unsigned int u = __builtin_bit_cast(unsigned int, x);
    hi = (unsigned short)(u >> 16);
    float r = x - bf2f(hi);
    lo = (unsigned short)(__builtin_bit_cast(unsigned int, r) >> 16);
}
// fp16 RTN split (for K): x = hi + lo to ~2^-22 rel
static __device__ __forceinline__ void splitf16(float x, unsigned short& hi, unsigned short& lo) {
    _Float16 h = (_Float16)x;
    hi = __builtin_bit_cast(unsigned short, h);
    _Float16 l = (_Float16)(x - (float)h);
    lo = __builtin_bit_cast(unsigned short, l);
}
// Q-row permutation: LDS row rho holds global q-row qperm(rho). Maps MFMA C-rows
// (lg*4+r) onto PV B-frag k-slots (lg*8+j) so P stays in registers.
static __device__ __forceinline__ int qperm(int r) {
    return ((r >> 5) << 5) | (((r >> 2) & 3) << 3) | (((r >> 4) & 1) << 2) | (r & 3);
}

// ---------------------------------------------------------------------------
// Pre-split the three weight matrices into bf16 hi/lo. grid (128, 3), 256 thr.
// ---------------------------------------------------------------------------
__global__ __launch_bounds__(256) void wsplit(
    const float* __restrict__ Wq, const float* __restrict__ Wk, const float* __restrict__ Wv,
    unsigned short* __restrict__ Whi, unsigned short* __restrict__ Wlo)
{
    const int z = blockIdx.y;
    const float* __restrict__ src = (z == 0) ? Wq : (z == 1) ? Wk : Wv;
    const int i = (blockIdx.x * 256 + threadIdx.x) * 8;
    float4 a = *(const float4*)&src[i];
    float4 b = *(const float4*)&src[i + 4];
    float v[8] = {a.x, a.y, a.z, a.w, b.x, b.y, b.z, b.w};
    unsigned short hb[8], lb[8];
    #pragma unroll
    for (int k = 0; k < 8; ++k) splitbf(v[k], hb[k], lb[k]);
    uint4 hv, lv;
    hv.x = (unsigned int)hb[0] | ((unsigned int)hb[1] << 16);
    hv.y = (unsigned int)hb[2] | ((unsigned int)hb[3] << 16);
    hv.z = (unsigned int)hb[4] | ((unsigned int)hb[5] << 16);
    hv.w = (unsigned int)hb[6] | ((unsigned int)hb[7] << 16);
    lv.x = (unsigned int)lb[0] | ((unsigned int)lb[1] << 16);
    lv.y = (unsigned int)lb[2] | ((unsigned int)lb[3] << 16);
    lv.z = (unsigned int)lb[4] | ((unsigned int)lb[5] << 16);
    lv.w = (unsigned int)lb[6] | ((unsigned int)lb[7] << 16);
    *(uint4*)&Whi[(size_t)z * WN + i] = hv;
    *(uint4*)&Wlo[(size_t)z * WN + i] = lv;
}

// ---------------------------------------------------------------------------
// Projection via 3-term split-bf16 MFMA. Y = X @ W^T + bias.
// grid (M/128, 512/64, 3), 256 thr (4 waves), BM=128 BN=64 BK=64.
//   z=0: Q -> fp16 single (Qh), pre-scaled 0.125
//   z=1: K -> fp16 (Khi,Klo)
//   z=2: V -> single fp16, transposed [b][h][d][T]
// ---------------------------------------------------------------------------
__global__ __launch_bounds__(256, 2) void proj_mfma(
    const float* __restrict__ X,
    const unsigned short* __restrict__ Whi, const unsigned short* __restrict__ Wlo,
    const float* __restrict__ bq, const float* __restrict__ bk, const float* __restrict__ bv,
    unsigned short* __restrict__ Qh,
    unsigned short* __restrict__ Khi, unsigned short* __restrict__ Klo,
    unsigned short* __restrict__ Vt)
{
    const int z = blockIdx.z;
    const int m0 = blockIdx.x * 128;
    const int n0 = blockIdx.y * 64;
    const int tid = threadIdx.x;
    const int wid = tid >> 6, lane = tid & 63;
    const int lg = lane >> 4, lr = lane & 15;

    __shared__ __attribute__((aligned(16))) unsigned short smem[384 * 72];
    auto Xh  = (unsigned short(*)[72])(smem);
    auto Xl  = (unsigned short(*)[72])(smem + 128 * 72);
    auto Wh2 = (unsigned short(*)[72])(smem + 256 * 72);
    auto Wl2 = (unsigned short(*)[72])(smem + 320 * 72);

    const unsigned short* __restrict__ Wh = Whi + (size_t)z * WN;
    const unsigned short* __restrict__ Wl = Wlo + (size_t)z * WN;

    f32x4 acc[2][4];
    #pragma unroll
    for (int rt = 0; rt < 2; ++rt)
        #pragma unroll
        for (int nt = 0; nt < 4; ++nt) acc[rt][nt] = (f32x4){0.f, 0.f, 0.f, 0.f};

    const int xr = tid >> 1;
    const int xc = (tid & 1) * 32;

    for (int k0 = 0; k0 < DM; k0 += 64) {
        #pragma unroll
        for (int w = 0; w < 4; ++w) {
            float4 fa = *(const float4*)&X[(size_t)(m0 + xr) * DM + k0 + xc + w * 8];
            float4 fb = *(const float4*)&X[(size_t)(m0 + xr) * DM + k0 + xc + w * 8 + 4];
            float v[8] = {fa.x, fa.y, fa.z, fa.w, fb.x, fb.y, fb.z, fb.w};
            unsigned short hb[8], lb[8];
            #pragma unroll
            for (int k = 0; k < 8; ++k) splitbf(v[k], hb[k], lb[k]);
            uint4 hv, lv;
            hv.x = (unsigned int)hb[0] | ((unsigned int)hb[1] << 16);
            hv.y = (unsigned int)hb[2] | ((unsigned int)hb[3] << 16);
            hv.z = (unsigned int)hb[4] | ((unsigned int)hb[5] << 16);
            hv.w = (unsigned int)hb[6] | ((unsigned int)hb[7] << 16);
            lv.x = (unsigned int)lb[0] | ((unsigned int)lb[1] << 16);
            lv.y = (unsigned int)lb[2] | ((unsigned int)lb[3] << 16);
            lv.z = (unsigned int)lb[4] | ((unsigned int)lb[5] << 16);
            lv.w = (unsigned int)lb[6] | ((unsigned int)lb[7] << 16);
            *(uint4*)&Xh[xr][xc + w * 8] = hv;
            *(uint4*)&Xl[xr][xc + w * 8] = lv;
        }
        #pragma unroll
        for (int it = 0; it < 2; ++it) {
            int i2 = it * 256 + tid;
            int fr = i2 >> 3, ch = i2 & 7;
            *(int4*)&Wh2[fr][ch * 8] = *(const int4*)&Wh[(size_t)(n0 + fr) * DM + k0 + ch * 8];
            *(int4*)&Wl2[fr][ch * 8] = *(const int4*)&Wl[(size_t)(n0 + fr) * DM + k0 + ch * 8];
        }
        __syncthreads();

        __builtin_amdgcn_s_setprio(1);
        #pragma unroll
        for (int kc = 0; kc < 2; ++kc) {
            short8 xa[2][2];
            #pragma unroll
            for (int rt = 0; rt < 2; ++rt) {
                xa[rt][0] = __builtin_bit_cast(short8, *(const int4*)&Xh[wid * 32 + rt * 16 + lr][kc * 32 + lg * 8]);
                xa[rt][1] = __builtin_bit_cast(short8, *(const int4*)&Xl[wid * 32 + rt * 16 + lr][kc * 32 + lg * 8]);
            }
            #pragma unroll
            for (int nt = 0; nt < 4; ++nt) {
                short8 wh = __builtin_bit_cast(short8, *(const int4*)&Wh2[nt * 16 + lr][kc * 32 + lg * 8]);
                short8 wl = __builtin_bit_cast(short8, *(const int4*)&Wl2[nt * 16 + lr][kc * 32 + lg * 8]);
                #pragma unroll
                for (int rt = 0; rt < 2; ++rt) {
                    acc[rt][nt] = __builtin_amdgcn_mfma_f32_16x16x32_bf16(xa[rt][0], wh, acc[rt][nt], 0, 0, 0);
                    acc[rt][nt] = __builtin_amdgcn_mfma_f32_16x16x32_bf16(xa[rt][1], wh, acc[rt][nt], 0, 0, 0);
                    acc[rt][nt] = __builtin_amdgcn_mfma_f32_16x16x32_bf16(xa[rt][0], wl, acc[rt][nt], 0, 0, 0);
                }
            }
        }
        __builtin_amdgcn_s_setprio(0);
        __syncthreads();
    }

    if (z < 2) {
        const float* __restrict__ bias = (z == 0) ? bq : bk;
        unsigned short* __restrict__ Hi = (z == 0) ? Qh : Khi;
        const float sc = (z == 0) ? 0.125f : 1.0f;
        #pragma unroll
        for (int nt = 0; nt < 4; ++nt) {
            int n = n0 + nt * 16 + lr;
            float bv_ = bias[n];
            #pragma unroll
            for (int rt = 0; rt < 2; ++rt)
                #pragma unroll
                for (int r = 0; r < 4; ++r) {
                    int m = m0 + wid * 32 + rt * 16 + lg * 4 + r;
                    float y = (acc[rt][nt][r] + bv_) * sc;
                    if (z == 0) {
                        Hi[(size_t)m * DM + n] =
                            __builtin_bit_cast(unsigned short, (_Float16)y);
                    } else {
                        unsigned short hb, lb;
                        splitf16(y, hb, lb);
                        Hi[(size_t)m * DM + n]  = hb;
                        Klo[(size_t)m * DM + n] = lb;
                    }
                }
        }
    } else {
        // V: single fp16, bounce through LDS, write transposed [b][h][d][T]
        unsigned short* Tk = (unsigned short*)smem;   // [64][136]
        #pragma unroll
        for (int nt = 0; nt < 4; ++nt) {
            int d = nt * 16 + lr;
            float bv_ = bv[n0 + d];
            #pragma unroll
            for (int rt = 0; rt < 2; ++rt)
                #pragma unroll
                for (int r = 0; r < 4; ++r) {
                    int t = wid * 32 + rt * 16 + lg * 4 + r;
                    float y = acc[rt][nt][r] + bv_;
                    Tk[d * 136 + t] = __builtin_bit_cast(unsigned short, (_Float16)y);
                }
        }
        __syncthreads();
        const int dl = tid >> 2, tq = tid & 3;
        const int bb = m0 >> 12, t0 = m0 & (TT - 1), h = n0 >> 6;
        size_t obase = ((size_t)((bb * NH + h) * HD + dl)) * TT + t0 + tq * 32;
        unsigned int w[16];
        #pragma unroll
        for (int k = 0; k < 16; ++k)
            w[k] = (unsigned int)Tk[dl * 136 + tq * 32 + 2 * k]
                 | ((unsigned int)Tk[dl * 136 + tq * 32 + 2 * k + 1] << 16);
        #pragma unroll
        for (int j = 0; j < 4; ++j) {
            uint4 wv = {w[4 * j], w[4 * j + 1], w[4 * j + 2], w[4 * j + 3]};
            *(uint4*)&Vt[obase + j * 8] = wv;
        }
    }
}

// ---------------------------------------------------------------------------
// Flash attention, fp16, 2-term QK (S = qh*(kh+kl); K full split in regs,
// Q single fp16 from LDS). PV single-term (P scaled by 2048, cancels).
// 256-q steps staged as FOUR 64-q sub-buffers; 4 compute passes share one
// barrier pair. 32 krows/wave, 128 krows/block, grid 512. LDS 64KB, 2/CU.
// ---------------------------------------------------------------------------
__global__ __launch_bounds__(256, 2) void attn_mfma(
    const unsigned short* __restrict__ Qh,
    const unsigned short* __restrict__ Khi, const unsigned short* __restrict__ Klo,
    const unsigned short* __restrict__ Vt,
    float* __restrict__ Out)
{
    const int flat = blockIdx.x;
    const int bh = flat & 15;                 // XCD-grouping: same bh -> same XCD
    const int r0 = (flat >> 4) * 128;
    const int b = bh >> 3, h = bh & 7;
    const int tid = threadIdx.x;
    const int wid = tid >> 6, lane = tid & 63;
    const int lg = lane >> 4, lr = lane & 15;
    const int wr0 = r0 + wid * 32;

    __shared__ __attribute__((aligned(16))) unsigned short Qs[4][64][64]; // [pass][perm q][d]
    __shared__ __attribute__((aligned(16))) unsigned short Vs[4][64][64]; // [pass][d][q]

    const size_t qbase = (size_t)b * TT * DM + h * HD;
    const size_t vbase = ((size_t)(b * NH + h)) * HD * TT;

    // K fragments resident in registers: [rowtile][kc][hi/lo]
    half8 kf[2][2][2];
    #pragma unroll
    for (int rt = 0; rt < 2; ++rt)
        #pragma unroll
        for (int kc = 0; kc < 2; ++kc) {
            size_t g = qbase + (size_t)(wr0 + rt * 16 + lr) * DM + kc * 32 + lg * 8;
            kf[rt][kc][0] = __builtin_bit_cast(half8, *(const int4*)&Khi[g]);
            kf[rt][kc][1] = __builtin_bit_cast(half8, *(const int4*)&Klo[g]);
        }

    // hoisted staging pointers (advance by constant per 256-q step)
    const unsigned short* qp[2];
    const unsigned short* vp[2];
    int slds[2];
    #pragma unroll
    for (int it = 0; it < 2; ++it) {
        int gi = it * 256 + tid;      // 0..511
        int fr = gi >> 3;             // 0..63
        int ch = (gi & 7) ^ (fr & 7);
        qp[it] = Qh + qbase + (size_t)qperm(fr) * DM + ch * 8;
        vp[it] = Vt + vbase + (size_t)fr * TT + ch * 8;
        slds[it] = (it * 256 + wid * 64) * 16;
    }

    float m_s[2], l_s[2];
    f32x4 oacc[2][4];
    #pragma unroll
    for (int rt = 0; rt < 2; ++rt) {
        m_s[rt] = -INFINITY; l_s[rt] = 0.f;
        #pragma unroll
        for (int dt = 0; dt < 4; ++dt) oacc[rt][dt] = (f32x4){0.f, 0.f, 0.f, 0.f};
    }

    for (int t = 0; t < TT / 256; ++t) {
        // ---- stage four 64-q sub-tiles (16 GLD16/thread), hoisted pointers
        #pragma unroll
        for (int tau = 0; tau < 4; ++tau) {
            #pragma unroll
            for (int it = 0; it < 2; ++it) {
                GLD16(qp[it] + (size_t)tau * 64 * DM, (char*)&Qs[tau][0][0] + slds[it]);
                GLD16(vp[it] + tau * 64,              (char*)&Vs[tau][0][0] + slds[it]);
            }
        }
        #pragma unroll
        for (int it = 0; it < 2; ++it) { qp[it] += 256 * DM; vp[it] += 256; }
        __syncthreads();

        // ---- four compute passes, no barrier between (read-only LDS)
        #pragma unroll
        for (int tau = 0; tau < 4; ++tau) {
            // S^T = Q @ K^T, 2-term (qh*kh + qh*kl)
            f32x4 sacc[2][4];
            #pragma unroll
            for (int rt = 0; rt < 2; ++rt)
                #pragma unroll
                for (int qt = 0; qt < 4; ++qt) sacc[rt][qt] = (f32x4){0.f, 0.f, 0.f, 0.f};
            __builtin_amdgcn_s_setprio(1);
            #pragma unroll
            for (int kc = 0; kc < 2; ++kc) {
                #pragma unroll
                for (int qt = 0; qt < 4; ++qt) {
                    int row = qt * 16 + lr;
                    int so = ((kc * 4 + lg) ^ (row & 7)) * 16;
                    half8 qv = __builtin_bit_cast(half8, *(const int4*)((const char*)&Qs[tau][row][0] + so));
                    #pragma unroll
                    for (int rt = 0; rt < 2; ++rt) {
                        sacc[rt][qt] = __builtin_amdgcn_mfma_f32_16x16x32_f16(qv, kf[rt][kc][0], sacc[rt][qt], 0, 0, 0);
                        sacc[rt][qt] = __builtin_amdgcn_mfma_f32_16x16x32_f16(qv, kf[rt][kc][1], sacc[rt][qt], 0, 0, 0);
                    }
                }
            }
            __builtin_amdgcn_s_setprio(0);

            // online softmax per krow + fp16 pack, scaled e^7.62
            unsigned int hp[2][4][2];
            #pragma unroll
            for (int rt = 0; rt < 2; ++rt) {
                float mx = -INFINITY;
                #pragma unroll
                for (int qt = 0; qt < 4; ++qt)
                    #pragma unroll
                    for (int r = 0; r < 4; ++r) mx = fmaxf(mx, sacc[rt][qt][r]);
                mx = fmaxf(mx, __shfl_xor(mx, 16));
                mx = fmaxf(mx, __shfl_xor(mx, 32));
                float nm = fmaxf(m_s[rt], mx);
                float al = __expf(m_s[rt] - nm);
                const float nmb = nm - 7.6246190f;       // ln(2048): p' = 2048*p
                float sum = 0.f;
                #pragma unroll
                for (int qt = 0; qt < 4; ++qt)
                    #pragma unroll
                    for (int r = 0; r < 4; ++r) {
                        float p = __expf(sacc[rt][qt][r] - nmb);
                        sacc[rt][qt][r] = p;
                        sum += p;
                    }
                sum += __shfl_xor(sum, 16);
                sum += __shfl_xor(sum, 32);
                m_s[rt] = nm;
                l_s[rt] = l_s[rt] * al + sum;
                #pragma unroll
                for (int qt = 0; qt < 4; ++qt)
                    #pragma unroll
                    for (int pp = 0; pp < 2; ++pp)
                        hp[rt][qt][pp] = __builtin_bit_cast(unsigned int,
                            __builtin_amdgcn_cvt_pkrtz(sacc[rt][qt][2 * pp], sacc[rt][qt][2 * pp + 1]));
                #pragma unroll
                for (int dt = 0; dt < 4; ++dt)
                    #pragma unroll
                    for (int r = 0; r < 4; ++r) oacc[rt][dt][r] *= al;
            }

            // out^T += V^T @ P, single fp16 term
            __builtin_amdgcn_s_setprio(1);
            #pragma unroll
            for (int c = 0; c < 2; ++c) {
                half8 pf[2];
                #pragma unroll
                for (int rt = 0; rt < 2; ++rt) {
                    int4 ph4 = {(int)hp[rt][2 * c][0], (int)hp[rt][2 * c][1],
                                (int)hp[rt][2 * c + 1][0], (int)hp[rt][2 * c + 1][1]};
                    pf[rt] = __builtin_bit_cast(half8, ph4);
                }
                #pragma unroll
                for (int dt = 0; dt < 4; ++dt) {
                    int row = dt * 16 + lr;
                    int so = ((c * 4 + lg) ^ (row & 7)) * 16;
                    half8 vh = __builtin_bit_cast(half8, *(const int4*)((const char*)&Vs[tau][row][0] + so));
                    #pragma unroll
                    for (int rt = 0; rt < 2; ++rt)
                        oacc[rt][dt] = __builtin_amdgcn_mfma_f32_16x16x32_f16(vh, pf[rt], oacc[rt][dt], 0, 0, 0);
                }
            }
            __builtin_amdgcn_s_setprio(0);
        }
        __syncthreads();
    }

    // epilogue: out[krow][d] = oacc / l  (scale 2048 cancels)
    #pragma unroll
    for (int rt = 0; rt < 2; ++rt) {
        float inv = __builtin_amdgcn_rcpf(l_s[rt]);
        int row = wr0 + rt * 16 + lr;
        #pragma unroll
        for (int dt = 0; dt < 4; ++dt)
            #pragma unroll
            for (int r = 0; r < 4; ++r)
                Out[((size_t)(b * TT + row)) * DM + h * HD + dt * 16 + lg * 4 + r] =
                    oacc[rt][dt][r] * inv;
    }
}

// ---------------------------------------------------------------------------
extern "C" void kernel_launch(void* const* d_in, const int* in_sizes, int n_in,
                              void* d_out, int out_size, void* d_ws, size_t ws_size,
                              hipStream_t stream)
{
    const float* x  = (const float*)d_in[0];
    const float* Wk = (const float*)d_in[1];
    const float* bk = (const float*)d_in[2];
    const float* Wq = (const float*)d_in[3];
    const float* bq = (const float*)d_in[4];
    const float* Wv = (const float*)d_in[5];
    const float* bv = (const float*)d_in[6];
    float* out = (float*)d_out;

    const size_t SZ = (size_t)2 * TT * DM;
    unsigned short* Qh  = (unsigned short*)d_ws;
    unsigned short* Khi = Qh + SZ;
    unsigned short* Klo = Khi + SZ;
    unsigned short* Vt  = Klo + SZ;
    unsigned short* Whi = Vt + SZ;
    unsigned short* Wlo = Whi + (size_t)3 * WN;

    wsplit<<<dim3(WN / 2048, 3), dim3(256), 0, stream>>>(Wq, Wk, Wv, Whi, Wlo);

    dim3 pgrid(2 * TT / 128, DM / 64, 3);
    proj_mfma<<<pgrid, dim3(256), 0, stream>>>(x, Whi, Wlo, bq, bk, bv,
                                               Qh, Khi, Klo, Vt);

    attn_mfma<<<dim3(512), dim3(256), 0, stream>>>(Qh, Khi, Klo, Vt, out);
}

// Round 12
// 190.539 us; speedup vs baseline: 1.2400x; 1.0291x over previous
//
#include <hip/hip_runtime.h>
#include <math.h>

#define TT 4096
#define DM 512
#define NH 8
#define HD 64
#define WN (DM * DM)   // 262144 elements per weight matrix

typedef float f32x4 __attribute__((ext_vector_type(4)));
typedef _Float16 half8 __attribute__((ext_vector_type(8)));

#define GLD16(gp, lp) __builtin_amdgcn_global_load_lds( \
    (const __attribute__((address_space(1))) void*)(gp), \
    (__attribute__((address_space(3))) void*)(lp), 16, 0, 0)

// fp16 RTN split: x = hi + lo to ~2^-22 rel
static __device__ __forceinline__ void splitf16(float x, unsigned short& hi, unsigned short& lo) {
    _Float16 h = (_Float16)x;
    hi = __builtin_bit_cast(unsigned short, h);
    _Float16 l = (_Float16)(x - (float)h);
    lo = __builtin_bit_cast(unsigned short, l);
}
// Q-row permutation: LDS row rho holds global q-row qperm(rho). Maps MFMA C-rows
// (lg*4+r) onto PV B-frag k-slots (lg*8+j) so P stays in registers.
static __device__ __forceinline__ int qperm(int r) {
    return ((r >> 5) << 5) | (((r >> 2) & 3) << 3) | (((r >> 4) & 1) << 2) | (r & 3);
}

// ---------------------------------------------------------------------------
// Pre-split the three weight matrices into fp16 hi/lo. grid (128, 3), 256 thr.
// ---------------------------------------------------------------------------
__global__ __launch_bounds__(256) void wsplit(
    const float* __restrict__ Wq, const float* __restrict__ Wk, const float* __restrict__ Wv,
    unsigned short* __restrict__ Whi, unsigned short* __restrict__ Wlo)
{
    const int z = blockIdx.y;
    const float* __restrict__ src = (z == 0) ? Wq : (z == 1) ? Wk : Wv;
    const int i = (blockIdx.x * 256 + threadIdx.x) * 8;
    float4 a = *(const float4*)&src[i];
    float4 b = *(const float4*)&src[i + 4];
    float v[8] = {a.x, a.y, a.z, a.w, b.x, b.y, b.z, b.w};
    unsigned short hb[8], lb[8];
    #pragma unroll
    for (int k = 0; k < 8; ++k) splitf16(v[k], hb[k], lb[k]);
    uint4 hv, lv;
    hv.x = (unsigned int)hb[0] | ((unsigned int)hb[1] << 16);
    hv.y = (unsigned int)hb[2] | ((unsigned int)hb[3] << 16);
    hv.z = (unsigned int)hb[4] | ((unsigned int)hb[5] << 16);
    hv.w = (unsigned int)hb[6] | ((unsigned int)hb[7] << 16);
    lv.x = (unsigned int)lb[0] | ((unsigned int)lb[1] << 16);
    lv.y = (unsigned int)lb[2] | ((unsigned int)lb[3] << 16);
    lv.z = (unsigned int)lb[4] | ((unsigned int)lb[5] << 16);
    lv.w = (unsigned int)lb[6] | ((unsigned int)lb[7] << 16);
    *(uint4*)&Whi[(size_t)z * WN + i] = hv;
    *(uint4*)&Wlo[(size_t)z * WN + i] = lv;
}

// ---------------------------------------------------------------------------
// Projection via 2-term fp16 MFMA: Y = X*(Wh + Wl) + bias, X single fp16.
// grid (M/128, 512/64, 3), 256 thr (4 waves), BM=128 BN=64 BK=64.
//   z=0: Q -> fp16 single (Qh), pre-scaled 0.125
//   z=1: K -> fp16 (Khi,Klo) split from fp32 acc
//   z=2: V -> single fp16, transposed [b][h][d][T]
// ---------------------------------------------------------------------------
__global__ __launch_bounds__(256, 2) void proj_mfma(
    const float* __restrict__ X,
    const unsigned short* __restrict__ Whi, const unsigned short* __restrict__ Wlo,
    const float* __restrict__ bq, const float* __restrict__ bk, const float* __restrict__ bv,
    unsigned short* __restrict__ Qh,
    unsigned short* __restrict__ Khi, unsigned short* __restrict__ Klo,
    unsigned short* __restrict__ Vt)
{
    const int z = blockIdx.z;
    const int m0 = blockIdx.x * 128;
    const int n0 = blockIdx.y * 64;
    const int tid = threadIdx.x;
    const int wid = tid >> 6, lane = tid & 63;
    const int lg = lane >> 4, lr = lane & 15;

    __shared__ __attribute__((aligned(16))) unsigned short smem[256 * 72];
    auto Xs  = (unsigned short(*)[72])(smem);              // 128 rows
    auto Wh2 = (unsigned short(*)[72])(smem + 128 * 72);   // 64 rows
    auto Wl2 = (unsigned short(*)[72])(smem + 192 * 72);   // 64 rows

    const unsigned short* __restrict__ Wh = Whi + (size_t)z * WN;
    const unsigned short* __restrict__ Wl = Wlo + (size_t)z * WN;

    f32x4 acc[2][4];
    #pragma unroll
    for (int rt = 0; rt < 2; ++rt)
        #pragma unroll
        for (int nt = 0; nt < 4; ++nt) acc[rt][nt] = (f32x4){0.f, 0.f, 0.f, 0.f};

    const int xr = tid >> 1;
    const int xc = (tid & 1) * 32;

    for (int k0 = 0; k0 < DM; k0 += 64) {
        // stage X (fp32 -> single fp16), 32 elems/thread
        #pragma unroll
        for (int w = 0; w < 4; ++w) {
            float4 fa = *(const float4*)&X[(size_t)(m0 + xr) * DM + k0 + xc + w * 8];
            float4 fb = *(const float4*)&X[(size_t)(m0 + xr) * DM + k0 + xc + w * 8 + 4];
            float v[8] = {fa.x, fa.y, fa.z, fa.w, fb.x, fb.y, fb.z, fb.w};
            unsigned int hw[4];
            #pragma unroll
            for (int k = 0; k < 4; ++k) {
                unsigned short h0 = __builtin_bit_cast(unsigned short, (_Float16)v[2 * k]);
                unsigned short h1 = __builtin_bit_cast(unsigned short, (_Float16)v[2 * k + 1]);
                hw[k] = (unsigned int)h0 | ((unsigned int)h1 << 16);
            }
            uint4 hv = {hw[0], hw[1], hw[2], hw[3]};
            *(uint4*)&Xs[xr][xc + w * 8] = hv;
        }
        #pragma unroll
        for (int it = 0; it < 2; ++it) {
            int i2 = it * 256 + tid;
            int fr = i2 >> 3, ch = i2 & 7;
            *(int4*)&Wh2[fr][ch * 8] = *(const int4*)&Wh[(size_t)(n0 + fr) * DM + k0 + ch * 8];
            *(int4*)&Wl2[fr][ch * 8] = *(const int4*)&Wl[(size_t)(n0 + fr) * DM + k0 + ch * 8];
        }
        __syncthreads();

        __builtin_amdgcn_s_setprio(1);
        #pragma unroll
        for (int kc = 0; kc < 2; ++kc) {
            half8 xa[2];
            #pragma unroll
            for (int rt = 0; rt < 2; ++rt)
                xa[rt] = __builtin_bit_cast(half8, *(const int4*)&Xs[wid * 32 + rt * 16 + lr][kc * 32 + lg * 8]);
            #pragma unroll
            for (int nt = 0; nt < 4; ++nt) {
                half8 wh = __builtin_bit_cast(half8, *(const int4*)&Wh2[nt * 16 + lr][kc * 32 + lg * 8]);
                half8 wl = __builtin_bit_cast(half8, *(const int4*)&Wl2[nt * 16 + lr][kc * 32 + lg * 8]);
                #pragma unroll
                for (int rt = 0; rt < 2; ++rt) {
                    acc[rt][nt] = __builtin_amdgcn_mfma_f32_16x16x32_f16(xa[rt], wh, acc[rt][nt], 0, 0, 0);
                    acc[rt][nt] = __builtin_amdgcn_mfma_f32_16x16x32_f16(xa[rt], wl, acc[rt][nt], 0, 0, 0);
                }
            }
        }
        __builtin_amdgcn_s_setprio(0);
        __syncthreads();
    }

    if (z < 2) {
        const float* __restrict__ bias = (z == 0) ? bq : bk;
        const float sc = (z == 0) ? 0.125f : 1.0f;
        #pragma unroll
        for (int nt = 0; nt < 4; ++nt) {
            int n = n0 + nt * 16 + lr;
            float bv_ = bias[n];
            #pragma unroll
            for (int rt = 0; rt < 2; ++rt)
                #pragma unroll
                for (int r = 0; r < 4; ++r) {
                    int m = m0 + wid * 32 + rt * 16 + lg * 4 + r;
                    float y = (acc[rt][nt][r] + bv_) * sc;
                    if (z == 0) {
                        Qh[(size_t)m * DM + n] =
                            __builtin_bit_cast(unsigned short, (_Float16)y);
                    } else {
                        unsigned short hb, lb;
                        splitf16(y, hb, lb);
                        Khi[(size_t)m * DM + n] = hb;
                        Klo[(size_t)m * DM + n] = lb;
                    }
                }
        }
    } else {
        // V: single fp16, bounce through LDS, write transposed [b][h][d][T]
        unsigned short* Tk = (unsigned short*)smem;   // [64][136]
        #pragma unroll
        for (int nt = 0; nt < 4; ++nt) {
            int d = nt * 16 + lr;
            float bv_ = bv[n0 + d];
            #pragma unroll
            for (int rt = 0; rt < 2; ++rt)
                #pragma unroll
                for (int r = 0; r < 4; ++r) {
                    int t = wid * 32 + rt * 16 + lg * 4 + r;
                    float y = acc[rt][nt][r] + bv_;
                    Tk[d * 136 + t] = __builtin_bit_cast(unsigned short, (_Float16)y);
                }
        }
        __syncthreads();
        const int dl = tid >> 2, tq = tid & 3;
        const int bb = m0 >> 12, t0 = m0 & (TT - 1), h = n0 >> 6;
        size_t obase = ((size_t)((bb * NH + h) * HD + dl)) * TT + t0 + tq * 32;
        unsigned int w[16];
        #pragma unroll
        for (int k = 0; k < 16; ++k)
            w[k] = (unsigned int)Tk[dl * 136 + tq * 32 + 2 * k]
                 | ((unsigned int)Tk[dl * 136 + tq * 32 + 2 * k + 1] << 16);
        #pragma unroll
        for (int j = 0; j < 4; ++j) {
            uint4 wv = {w[4 * j], w[4 * j + 1], w[4 * j + 2], w[4 * j + 3]};
            *(uint4*)&Vt[obase + j * 8] = wv;
        }
    }
}

// ---------------------------------------------------------------------------
// Flash attention, fp16, 2-term QK, cross-pass pipeline: QK(tau+1) issued
// before softmax+PV(tau) so QK's MFMAs overlap softmax's VALU chain.
// 256-q steps, 4 passes per barrier pair. 32 krows/wave, 128 krows/block,
// grid 512. LDS 64KB, 2 blocks/CU.
// ---------------------------------------------------------------------------
__global__ __launch_bounds__(256, 2) void attn_mfma(
    const unsigned short* __restrict__ Qh,
    const unsigned short* __restrict__ Khi, const unsigned short* __restrict__ Klo,
    const unsigned short* __restrict__ Vt,
    float* __restrict__ Out)
{
    const int flat = blockIdx.x;
    const int bh = flat & 15;                 // XCD-grouping: same bh -> same XCD
    const int r0 = (flat >> 4) * 128;
    const int b = bh >> 3, h = bh & 7;
    const int tid = threadIdx.x;
    const int wid = tid >> 6, lane = tid & 63;
    const int lg = lane >> 4, lr = lane & 15;
    const int wr0 = r0 + wid * 32;

    __shared__ __attribute__((aligned(16))) unsigned short Qs[4][64][64]; // [pass][perm q][d]
    __shared__ __attribute__((aligned(16))) unsigned short Vs[4][64][64]; // [pass][d][q]

    const size_t qbase = (size_t)b * TT * DM + h * HD;
    const size_t vbase = ((size_t)(b * NH + h)) * HD * TT;

    // K fragments resident in registers: [rowtile][kc][hi/lo]
    half8 kf[2][2][2];
    #pragma unroll
    for (int rt = 0; rt < 2; ++rt)
        #pragma unroll
        for (int kc = 0; kc < 2; ++kc) {
            size_t g = qbase + (size_t)(wr0 + rt * 16 + lr) * DM + kc * 32 + lg * 8;
            kf[rt][kc][0] = __builtin_bit_cast(half8, *(const int4*)&Khi[g]);
            kf[rt][kc][1] = __builtin_bit_cast(half8, *(const int4*)&Klo[g]);
        }

    // hoisted staging pointers (advance by constant per 256-q step)
    const unsigned short* qp[2];
    const unsigned short* vp[2];
    int slds[2];
    #pragma unroll
    for (int it = 0; it < 2; ++it) {
        int gi = it * 256 + tid;      // 0..511
        int fr = gi >> 3;             // 0..63
        int ch = (gi & 7) ^ (fr & 7);
        qp[it] = Qh + qbase + (size_t)qperm(fr) * DM + ch * 8;
        vp[it] = Vt + vbase + (size_t)fr * TT + ch * 8;
        slds[it] = (it * 256 + wid * 64) * 16;
    }

    float m_s[2], l_s[2];
    f32x4 oacc[2][4];
    #pragma unroll
    for (int rt = 0; rt < 2; ++rt) {
        m_s[rt] = -INFINITY; l_s[rt] = 0.f;
        #pragma unroll
        for (int dt = 0; dt < 4; ++dt) oacc[rt][dt] = (f32x4){0.f, 0.f, 0.f, 0.f};
    }

    // QK: compute S^T for pass tau into sacc (2-term: qh*kh + qh*kl)
    auto QK = [&](int tau, f32x4 (&sacc)[2][4]) {
        #pragma unroll
        for (int rt = 0; rt < 2; ++rt)
            #pragma unroll
            for (int qt = 0; qt < 4; ++qt) sacc[rt][qt] = (f32x4){0.f, 0.f, 0.f, 0.f};
        __builtin_amdgcn_s_setprio(1);
        #pragma unroll
        for (int kc = 0; kc < 2; ++kc) {
            #pragma unroll
            for (int qt = 0; qt < 4; ++qt) {
                int row = qt * 16 + lr;
                int so = ((kc * 4 + lg) ^ (row & 7)) * 16;
                half8 qv = __builtin_bit_cast(half8, *(const int4*)((const char*)&Qs[tau][row][0] + so));
                #pragma unroll
                for (int rt = 0; rt < 2; ++rt) {
                    sacc[rt][qt] = __builtin_amdgcn_mfma_f32_16x16x32_f16(qv, kf[rt][kc][0], sacc[rt][qt], 0, 0, 0);
                    sacc[rt][qt] = __builtin_amdgcn_mfma_f32_16x16x32_f16(qv, kf[rt][kc][1], sacc[rt][qt], 0, 0, 0);
                }
            }
        }
        __builtin_amdgcn_s_setprio(0);
    };

    // SMPV: softmax + PV for pass tau consuming sacc
    auto SMPV = [&](int tau, f32x4 (&sacc)[2][4]) {
        unsigned int hp[2][4][2];
        #pragma unroll
        for (int rt = 0; rt < 2; ++rt) {
            float mx = -INFINITY;
            #pragma unroll
            for (int qt = 0; qt < 4; ++qt)
                #pragma unroll
                for (int r = 0; r < 4; ++r) mx = fmaxf(mx, sacc[rt][qt][r]);
            mx = fmaxf(mx, __shfl_xor(mx, 16));
            mx = fmaxf(mx, __shfl_xor(mx, 32));
            float nm = fmaxf(m_s[rt], mx);
            float al = __expf(m_s[rt] - nm);
            const float nmb = nm - 7.6246190f;       // ln(2048): p' = 2048*p
            float sum = 0.f;
            #pragma unroll
            for (int qt = 0; qt < 4; ++qt)
                #pragma unroll
                for (int r = 0; r < 4; ++r) {
                    float p = __expf(sacc[rt][qt][r] - nmb);
                    sacc[rt][qt][r] = p;
                    sum += p;
                }
            sum += __shfl_xor(sum, 16);
            sum += __shfl_xor(sum, 32);
            m_s[rt] = nm;
            l_s[rt] = l_s[rt] * al + sum;
            #pragma unroll
            for (int qt = 0; qt < 4; ++qt)
                #pragma unroll
                for (int pp = 0; pp < 2; ++pp)
                    hp[rt][qt][pp] = __builtin_bit_cast(unsigned int,
                        __builtin_amdgcn_cvt_pkrtz(sacc[rt][qt][2 * pp], sacc[rt][qt][2 * pp + 1]));
            #pragma unroll
            for (int dt = 0; dt < 4; ++dt)
                #pragma unroll
                for (int r = 0; r < 4; ++r) oacc[rt][dt][r] *= al;
        }
        __builtin_amdgcn_s_setprio(1);
        #pragma unroll
        for (int c = 0; c < 2; ++c) {
            half8 pf[2];
            #pragma unroll
            for (int rt = 0; rt < 2; ++rt) {
                int4 ph4 = {(int)hp[rt][2 * c][0], (int)hp[rt][2 * c][1],
                            (int)hp[rt][2 * c + 1][0], (int)hp[rt][2 * c + 1][1]};
                pf[rt] = __builtin_bit_cast(half8, ph4);
            }
            #pragma unroll
            for (int dt = 0; dt < 4; ++dt) {
                int row = dt * 16 + lr;
                int so = ((c * 4 + lg) ^ (row & 7)) * 16;
                half8 vh = __builtin_bit_cast(half8, *(const int4*)((const char*)&Vs[tau][row][0] + so));
                #pragma unroll
                for (int rt = 0; rt < 2; ++rt)
                    oacc[rt][dt] = __builtin_amdgcn_mfma_f32_16x16x32_f16(vh, pf[rt], oacc[rt][dt], 0, 0, 0);
            }
        }
        __builtin_amdgcn_s_setprio(0);
    };

    f32x4 sA[2][4], sB[2][4];

    for (int t = 0; t < TT / 256; ++t) {
        // ---- stage four 64-q sub-tiles (16 GLD16/thread), hoisted pointers
        #pragma unroll
        for (int tau = 0; tau < 4; ++tau) {
            #pragma unroll
            for (int it = 0; it < 2; ++it) {
                GLD16(qp[it] + (size_t)tau * 64 * DM, (char*)&Qs[tau][0][0] + slds[it]);
                GLD16(vp[it] + tau * 64,              (char*)&Vs[tau][0][0] + slds[it]);
            }
        }
        #pragma unroll
        for (int it = 0; it < 2; ++it) { qp[it] += 256 * DM; vp[it] += 256; }
        __syncthreads();

        // ---- 4 passes, cross-pass pipelined: QK(tau+1) before SMPV(tau)
        QK(0, sA);
        QK(1, sB); SMPV(0, sA);
        QK(2, sA); SMPV(1, sB);
        QK(3, sB); SMPV(2, sA);
                   SMPV(3, sB);
        __syncthreads();
    }

    // epilogue: out[krow][d] = oacc / l  (scale 2048 cancels)
    #pragma unroll
    for (int rt = 0; rt < 2; ++rt) {
        float inv = __builtin_amdgcn_rcpf(l_s[rt]);
        int row = wr0 + rt * 16 + lr;
        #pragma unroll
        for (int dt = 0; dt < 4; ++dt)
            #pragma unroll
            for (int r = 0; r < 4; ++r)
                Out[((size_t)(b * TT + row)) * DM + h * HD + dt * 16 + lg * 4 + r] =
                    oacc[rt][dt][r] * inv;
    }
}

// ---------------------------------------------------------------------------
extern "C" void kernel_launch(void* const* d_in, const int* in_sizes, int n_in,
                              void* d_out, int out_size, void* d_ws, size_t ws_size,
                              hipStream_t stream)
{
    const float* x  = (const float*)d_in[0];
    const float* Wk = (const float*)d_in[1];
    const float* bk = (const float*)d_in[2];
    const float* Wq = (const float*)d_in[3];
    const float* bq = (const float*)d_in[4];
    const float* Wv = (const float*)d_in[5];
    const float* bv = (const float*)d_in[6];
    float* out = (float*)d_out;

    const size_t SZ = (size_t)2 * TT * DM;
    unsigned short* Qh  = (unsigned short*)d_ws;
    unsigned short* Khi = Qh + SZ;
    unsigned short* Klo = Khi + SZ;
    unsigned short* Vt  = Klo + SZ;
    unsigned short* Whi = Vt + SZ;
    unsigned short* Wlo = Whi + (size_t)3 * WN;

    wsplit<<<dim3(WN / 2048, 3), dim3(256), 0, stream>>>(Wq, Wk, Wv, Whi, Wlo);

    dim3 pgrid(2 * TT / 128, DM / 64, 3);
    proj_mfma<<<pgrid, dim3(256), 0, stream>>>(x, Whi, Wlo, bq, bk, bv,
                                               Qh, Khi, Klo, Vt);

    attn_mfma<<<dim3(512), dim3(256), 0, stream>>>(Qh, Khi, Klo, Vt, out);
}

// Round 13
// 174.706 us; speedup vs baseline: 1.3523x; 1.0906x over previous
//
#include <hip/hip_runtime.h>
#include <math.h>

#define TT 4096
#define DM 512
#define NH 8
#define HD 64
#define WN (DM * DM)   // 262144 elements per weight matrix

typedef float f32x4 __attribute__((ext_vector_type(4)));
typedef _Float16 half8 __attribute__((ext_vector_type(8)));

#define GLD16(gp, lp) __builtin_amdgcn_global_load_lds( \
    (const __attribute__((address_space(1))) void*)(gp), \
    (__attribute__((address_space(3))) void*)(lp), 16, 0, 0)

// fp16 RTN split: x = hi + lo to ~2^-22 rel
static __device__ __forceinline__ void splitf16(float x, unsigned short& hi, unsigned short& lo) {
    _Float16 h = (_Float16)x;
    hi = __builtin_bit_cast(unsigned short, h);
    _Float16 l = (_Float16)(x - (float)h);
    lo = __builtin_bit_cast(unsigned short, l);
}
// Q-row permutation: LDS row rho holds global q-row qperm(rho). Maps MFMA C-rows
// (lg*4+r) onto PV B-frag k-slots (lg*8+j) so P stays in registers.
static __device__ __forceinline__ int qperm(int r) {
    return ((r >> 5) << 5) | (((r >> 2) & 3) << 3) | (((r >> 4) & 1) << 2) | (r & 3);
}

// ---------------------------------------------------------------------------
// Pre-split the three weight matrices into fp16 hi/lo. grid (128, 3), 256 thr.
// ---------------------------------------------------------------------------
__global__ __launch_bounds__(256) void wsplit(
    const float* __restrict__ Wq, const float* __restrict__ Wk, const float* __restrict__ Wv,
    unsigned short* __restrict__ Whi, unsigned short* __restrict__ Wlo)
{
    const int z = blockIdx.y;
    const float* __restrict__ src = (z == 0) ? Wq : (z == 1) ? Wk : Wv;
    const int i = (blockIdx.x * 256 + threadIdx.x) * 8;
    float4 a = *(const float4*)&src[i];
    float4 b = *(const float4*)&src[i + 4];
    float v[8] = {a.x, a.y, a.z, a.w, b.x, b.y, b.z, b.w};
    unsigned short hb[8], lb[8];
    #pragma unroll
    for (int k = 0; k < 8; ++k) splitf16(v[k], hb[k], lb[k]);
    uint4 hv, lv;
    hv.x = (unsigned int)hb[0] | ((unsigned int)hb[1] << 16);
    hv.y = (unsigned int)hb[2] | ((unsigned int)hb[3] << 16);
    hv.z = (unsigned int)hb[4] | ((unsigned int)hb[5] << 16);
    hv.w = (unsigned int)hb[6] | ((unsigned int)hb[7] << 16);
    lv.x = (unsigned int)lb[0] | ((unsigned int)lb[1] << 16);
    lv.y = (unsigned int)lb[2] | ((unsigned int)lb[3] << 16);
    lv.z = (unsigned int)lb[4] | ((unsigned int)lb[5] << 16);
    lv.w = (unsigned int)lb[6] | ((unsigned int)lb[7] << 16);
    *(uint4*)&Whi[(size_t)z * WN + i] = hv;
    *(uint4*)&Wlo[(size_t)z * WN + i] = lv;
}

// ---------------------------------------------------------------------------
// Projection via 2-term fp16 MFMA: Y = X*(Wh + Wl) + bias, X single fp16.
// grid (M/128, 512/64, 3), 256 thr (4 waves), BM=128 BN=64 BK=64.
//   z=0: Q -> fp16 single (Qh), pre-scaled 0.125
//   z=1: K -> fp16 (Khi,Klo) split from fp32 acc
//   z=2: V -> single fp16, transposed [b][h][d][T]
// ---------------------------------------------------------------------------
__global__ __launch_bounds__(256, 2) void proj_mfma(
    const float* __restrict__ X,
    const unsigned short* __restrict__ Whi, const unsigned short* __restrict__ Wlo,
    const float* __restrict__ bq, const float* __restrict__ bk, const float* __restrict__ bv,
    unsigned short* __restrict__ Qh,
    unsigned short* __restrict__ Khi, unsigned short* __restrict__ Klo,
    unsigned short* __restrict__ Vt)
{
    const int z = blockIdx.z;
    const int m0 = blockIdx.x * 128;
    const int n0 = blockIdx.y * 64;
    const int tid = threadIdx.x;
    const int wid = tid >> 6, lane = tid & 63;
    const int lg = lane >> 4, lr = lane & 15;

    __shared__ __attribute__((aligned(16))) unsigned short smem[256 * 72];
    auto Xs  = (unsigned short(*)[72])(smem);              // 128 rows
    auto Wh2 = (unsigned short(*)[72])(smem + 128 * 72);   // 64 rows
    auto Wl2 = (unsigned short(*)[72])(smem + 192 * 72);   // 64 rows

    const unsigned short* __restrict__ Wh = Whi + (size_t)z * WN;
    const unsigned short* __restrict__ Wl = Wlo + (size_t)z * WN;

    f32x4 acc[2][4];
    #pragma unroll
    for (int rt = 0; rt < 2; ++rt)
        #pragma unroll
        for (int nt = 0; nt < 4; ++nt) acc[rt][nt] = (f32x4){0.f, 0.f, 0.f, 0.f};

    const int xr = tid >> 1;
    const int xc = (tid & 1) * 32;

    for (int k0 = 0; k0 < DM; k0 += 64) {
        // stage X (fp32 -> single fp16), 32 elems/thread
        #pragma unroll
        for (int w = 0; w < 4; ++w) {
            float4 fa = *(const float4*)&X[(size_t)(m0 + xr) * DM + k0 + xc + w * 8];
            float4 fb = *(const float4*)&X[(size_t)(m0 + xr) * DM + k0 + xc + w * 8 + 4];
            float v[8] = {fa.x, fa.y, fa.z, fa.w, fb.x, fb.y, fb.z, fb.w};
            unsigned int hw[4];
            #pragma unroll
            for (int k = 0; k < 4; ++k) {
                unsigned short h0 = __builtin_bit_cast(unsigned short, (_Float16)v[2 * k]);
                unsigned short h1 = __builtin_bit_cast(unsigned short, (_Float16)v[2 * k + 1]);
                hw[k] = (unsigned int)h0 | ((unsigned int)h1 << 16);
            }
            uint4 hv = {hw[0], hw[1], hw[2], hw[3]};
            *(uint4*)&Xs[xr][xc + w * 8] = hv;
        }
        #pragma unroll
        for (int it = 0; it < 2; ++it) {
            int i2 = it * 256 + tid;
            int fr = i2 >> 3, ch = i2 & 7;
            *(int4*)&Wh2[fr][ch * 8] = *(const int4*)&Wh[(size_t)(n0 + fr) * DM + k0 + ch * 8];
            *(int4*)&Wl2[fr][ch * 8] = *(const int4*)&Wl[(size_t)(n0 + fr) * DM + k0 + ch * 8];
        }
        __syncthreads();

        __builtin_amdgcn_s_setprio(1);
        #pragma unroll
        for (int kc = 0; kc < 2; ++kc) {
            half8 xa[2];
            #pragma unroll
            for (int rt = 0; rt < 2; ++rt)
                xa[rt] = __builtin_bit_cast(half8, *(const int4*)&Xs[wid * 32 + rt * 16 + lr][kc * 32 + lg * 8]);
            #pragma unroll
            for (int nt = 0; nt < 4; ++nt) {
                half8 wh = __builtin_bit_cast(half8, *(const int4*)&Wh2[nt * 16 + lr][kc * 32 + lg * 8]);
                half8 wl = __builtin_bit_cast(half8, *(const int4*)&Wl2[nt * 16 + lr][kc * 32 + lg * 8]);
                #pragma unroll
                for (int rt = 0; rt < 2; ++rt) {
                    acc[rt][nt] = __builtin_amdgcn_mfma_f32_16x16x32_f16(xa[rt], wh, acc[rt][nt], 0, 0, 0);
                    acc[rt][nt] = __builtin_amdgcn_mfma_f32_16x16x32_f16(xa[rt], wl, acc[rt][nt], 0, 0, 0);
                }
            }
        }
        __builtin_amdgcn_s_setprio(0);
        __syncthreads();
    }

    if (z < 2) {
        const float* __restrict__ bias = (z == 0) ? bq : bk;
        const float sc = (z == 0) ? 0.125f : 1.0f;
        #pragma unroll
        for (int nt = 0; nt < 4; ++nt) {
            int n = n0 + nt * 16 + lr;
            float bv_ = bias[n];
            #pragma unroll
            for (int rt = 0; rt < 2; ++rt)
                #pragma unroll
                for (int r = 0; r < 4; ++r) {
                    int m = m0 + wid * 32 + rt * 16 + lg * 4 + r;
                    float y = (acc[rt][nt][r] + bv_) * sc;
                    if (z == 0) {
                        Qh[(size_t)m * DM + n] =
                            __builtin_bit_cast(unsigned short, (_Float16)y);
                    } else {
                        unsigned short hb, lb;
                        splitf16(y, hb, lb);
                        Khi[(size_t)m * DM + n] = hb;
                        Klo[(size_t)m * DM + n] = lb;
                    }
                }
        }
    } else {
        // V: single fp16, bounce through LDS, write transposed [b][h][d][T]
        unsigned short* Tk = (unsigned short*)smem;   // [64][136]
        #pragma unroll
        for (int nt = 0; nt < 4; ++nt) {
            int d = nt * 16 + lr;
            float bv_ = bv[n0 + d];
            #pragma unroll
            for (int rt = 0; rt < 2; ++rt)
                #pragma unroll
                for (int r = 0; r < 4; ++r) {
                    int t = wid * 32 + rt * 16 + lg * 4 + r;
                    float y = acc[rt][nt][r] + bv_;
                    Tk[d * 136 + t] = __builtin_bit_cast(unsigned short, (_Float16)y);
                }
        }
        __syncthreads();
        const int dl = tid >> 2, tq = tid & 3;
        const int bb = m0 >> 12, t0 = m0 & (TT - 1), h = n0 >> 6;
        size_t obase = ((size_t)((bb * NH + h) * HD + dl)) * TT + t0 + tq * 32;
        unsigned int w[16];
        #pragma unroll
        for (int k = 0; k < 16; ++k)
            w[k] = (unsigned int)Tk[dl * 136 + tq * 32 + 2 * k]
                 | ((unsigned int)Tk[dl * 136 + tq * 32 + 2 * k + 1] << 16);
        #pragma unroll
        for (int j = 0; j < 4; ++j) {
            uint4 wv = {w[4 * j], w[4 * j + 1], w[4 * j + 2], w[4 * j + 3]};
            *(uint4*)&Vt[obase + j * 8] = wv;
        }
    }
}

// ---------------------------------------------------------------------------
// Flash attention, fp16, 2-term QK, defer-max softmax (T13) + l-via-MFMA
// (ones-row A-fragment accumulates the softmax denominator on the matrix
// pipe). Common path per pass: local fmax + ballot + exp + cvt; no shfl,
// no rescale. 256-q steps, 4 passes per barrier pair. 32 krows/wave,
// 128 krows/block, grid 512. LDS 64KB, 2 blocks/CU.
// ---------------------------------------------------------------------------
__global__ __launch_bounds__(256, 2) void attn_mfma(
    const unsigned short* __restrict__ Qh,
    const unsigned short* __restrict__ Khi, const unsigned short* __restrict__ Klo,
    const unsigned short* __restrict__ Vt,
    float* __restrict__ Out)
{
    const int flat = blockIdx.x;
    const int bh = flat & 15;                 // XCD-grouping: same bh -> same XCD
    const int r0 = (flat >> 4) * 128;
    const int b = bh >> 3, h = bh & 7;
    const int tid = threadIdx.x;
    const int wid = tid >> 6, lane = tid & 63;
    const int lg = lane >> 4, lr = lane & 15;
    const int wr0 = r0 + wid * 32;

    __shared__ __attribute__((aligned(16))) unsigned short Qs[4][64][64]; // [pass][perm q][d]
    __shared__ __attribute__((aligned(16))) unsigned short Vs[4][64][64]; // [pass][d][q]

    const size_t qbase = (size_t)b * TT * DM + h * HD;
    const size_t vbase = ((size_t)(b * NH + h)) * HD * TT;

    // K fragments resident in registers: [rowtile][kc][hi/lo]
    half8 kf[2][2][2];
    #pragma unroll
    for (int rt = 0; rt < 2; ++rt)
        #pragma unroll
        for (int kc = 0; kc < 2; ++kc) {
            size_t g = qbase + (size_t)(wr0 + rt * 16 + lr) * DM + kc * 32 + lg * 8;
            kf[rt][kc][0] = __builtin_bit_cast(half8, *(const int4*)&Khi[g]);
            kf[rt][kc][1] = __builtin_bit_cast(half8, *(const int4*)&Klo[g]);
        }

    // ones A-fragment: A[0][k] = 1 for all k, other rows 0 -> row 0 of the
    // PV-shaped mfma accumulates sum_q P[q][krow] (the softmax denominator).
    half8 ones;
    {
        _Float16 o = (_Float16)((lr == 0) ? 1.0f : 0.0f);
        #pragma unroll
        for (int j = 0; j < 8; ++j) ones[j] = o;
    }

    // hoisted staging pointers (advance by constant per 256-q step)
    const unsigned short* qp[2];
    const unsigned short* vp[2];
    int slds[2];
    #pragma unroll
    for (int it = 0; it < 2; ++it) {
        int gi = it * 256 + tid;      // 0..511
        int fr = gi >> 3;             // 0..63
        int ch = (gi & 7) ^ (fr & 7);
        qp[it] = Qh + qbase + (size_t)qperm(fr) * DM + ch * 8;
        vp[it] = Vt + vbase + (size_t)fr * TT + ch * 8;
        slds[it] = (it * 256 + wid * 64) * 16;
    }

    float m_s[2];
    f32x4 lacc[2];
    f32x4 oacc[2][4];
    #pragma unroll
    for (int rt = 0; rt < 2; ++rt) {
        m_s[rt] = -INFINITY;
        lacc[rt] = (f32x4){0.f, 0.f, 0.f, 0.f};
        #pragma unroll
        for (int dt = 0; dt < 4; ++dt) oacc[rt][dt] = (f32x4){0.f, 0.f, 0.f, 0.f};
    }

    // QK: compute S^T for pass tau into sacc (2-term: qh*kh + qh*kl)
    auto QK = [&](int tau, f32x4 (&sacc)[2][4]) {
        #pragma unroll
        for (int rt = 0; rt < 2; ++rt)
            #pragma unroll
            for (int qt = 0; qt < 4; ++qt) sacc[rt][qt] = (f32x4){0.f, 0.f, 0.f, 0.f};
        __builtin_amdgcn_s_setprio(1);
        #pragma unroll
        for (int kc = 0; kc < 2; ++kc) {
            #pragma unroll
            for (int qt = 0; qt < 4; ++qt) {
                int row = qt * 16 + lr;
                int so = ((kc * 4 + lg) ^ (row & 7)) * 16;
                half8 qv = __builtin_bit_cast(half8, *(const int4*)((const char*)&Qs[tau][row][0] + so));
                #pragma unroll
                for (int rt = 0; rt < 2; ++rt) {
                    sacc[rt][qt] = __builtin_amdgcn_mfma_f32_16x16x32_f16(qv, kf[rt][kc][0], sacc[rt][qt], 0, 0, 0);
                    sacc[rt][qt] = __builtin_amdgcn_mfma_f32_16x16x32_f16(qv, kf[rt][kc][1], sacc[rt][qt], 0, 0, 0);
                }
            }
        }
        __builtin_amdgcn_s_setprio(0);
    };

    // SMPV: defer-max softmax + PV for pass tau consuming sacc
    auto SMPV = [&](int tau, f32x4 (&sacc)[2][4]) {
        unsigned int hp[2][4][2];
        #pragma unroll
        for (int rt = 0; rt < 2; ++rt) {
            // local max over this lane's 16 scores
            float mx = -INFINITY;
            #pragma unroll
            for (int qt = 0; qt < 4; ++qt)
                #pragma unroll
                for (int r = 0; r < 4; ++r) mx = fmaxf(mx, sacc[rt][qt][r]);
            // defer-max: rescale only when max grew beyond THR=8 (p <= e^8)
            if (!__all(mx - m_s[rt] <= 8.0f)) {
                mx = fmaxf(mx, __shfl_xor(mx, 16));
                mx = fmaxf(mx, __shfl_xor(mx, 32));
                float nm = fmaxf(m_s[rt], mx);
                float al = __expf(m_s[rt] - nm);
                m_s[rt] = nm;
                #pragma unroll
                for (int dt = 0; dt < 4; ++dt)
                    #pragma unroll
                    for (int r = 0; r < 4; ++r) oacc[rt][dt][r] *= al;
                #pragma unroll
                for (int r = 0; r < 4; ++r) lacc[rt][r] *= al;
            }
            const float nmb = m_s[rt];
            #pragma unroll
            for (int qt = 0; qt < 4; ++qt)
                #pragma unroll
                for (int r = 0; r < 4; ++r)
                    sacc[rt][qt][r] = __expf(sacc[rt][qt][r] - nmb);
            #pragma unroll
            for (int qt = 0; qt < 4; ++qt)
                #pragma unroll
                for (int pp = 0; pp < 2; ++pp)
                    hp[rt][qt][pp] = __builtin_bit_cast(unsigned int,
                        __builtin_amdgcn_cvt_pkrtz(sacc[rt][qt][2 * pp], sacc[rt][qt][2 * pp + 1]));
        }
        __builtin_amdgcn_s_setprio(1);
        #pragma unroll
        for (int c = 0; c < 2; ++c) {
            half8 pf[2];
            #pragma unroll
            for (int rt = 0; rt < 2; ++rt) {
                int4 ph4 = {(int)hp[rt][2 * c][0], (int)hp[rt][2 * c][1],
                            (int)hp[rt][2 * c + 1][0], (int)hp[rt][2 * c + 1][1]};
                pf[rt] = __builtin_bit_cast(half8, ph4);
            }
            // denominator: row-0-ones A frag sums P over q on the MFMA pipe
            #pragma unroll
            for (int rt = 0; rt < 2; ++rt)
                lacc[rt] = __builtin_amdgcn_mfma_f32_16x16x32_f16(ones, pf[rt], lacc[rt], 0, 0, 0);
            #pragma unroll
            for (int dt = 0; dt < 4; ++dt) {
                int row = dt * 16 + lr;
                int so = ((c * 4 + lg) ^ (row & 7)) * 16;
                half8 vh = __builtin_bit_cast(half8, *(const int4*)((const char*)&Vs[tau][row][0] + so));
                #pragma unroll
                for (int rt = 0; rt < 2; ++rt)
                    oacc[rt][dt] = __builtin_amdgcn_mfma_f32_16x16x32_f16(vh, pf[rt], oacc[rt][dt], 0, 0, 0);
            }
        }
        __builtin_amdgcn_s_setprio(0);
    };

    f32x4 sA[2][4], sB[2][4];

    for (int t = 0; t < TT / 256; ++t) {
        // ---- stage four 64-q sub-tiles (16 GLD16/thread), hoisted pointers
        #pragma unroll
        for (int tau = 0; tau < 4; ++tau) {
            #pragma unroll
            for (int it = 0; it < 2; ++it) {
                GLD16(qp[it] + (size_t)tau * 64 * DM, (char*)&Qs[tau][0][0] + slds[it]);
                GLD16(vp[it] + tau * 64,              (char*)&Vs[tau][0][0] + slds[it]);
            }
        }
        #pragma unroll
        for (int it = 0; it < 2; ++it) { qp[it] += 256 * DM; vp[it] += 256; }
        __syncthreads();

        // ---- 4 passes, cross-pass pipelined: QK(tau+1) before SMPV(tau)
        QK(0, sA);
        QK(1, sB); SMPV(0, sA);
        QK(2, sA); SMPV(1, sB);
        QK(3, sB); SMPV(2, sA);
                   SMPV(3, sB);
        __syncthreads();
    }

    // epilogue: out[krow][d] = oacc / l ; l sits in lane lr (row 0) of lacc
    #pragma unroll
    for (int rt = 0; rt < 2; ++rt) {
        float lfull = __shfl(lacc[rt][0], lr);
        float inv = __builtin_amdgcn_rcpf(lfull);
        int row = wr0 + rt * 16 + lr;
        #pragma unroll
        for (int dt = 0; dt < 4; ++dt)
            #pragma unroll
            for (int r = 0; r < 4; ++r)
                Out[((size_t)(b * TT + row)) * DM + h * HD + dt * 16 + lg * 4 + r] =
                    oacc[rt][dt][r] * inv;
    }
}

// ---------------------------------------------------------------------------
extern "C" void kernel_launch(void* const* d_in, const int* in_sizes, int n_in,
                              void* d_out, int out_size, void* d_ws, size_t ws_size,
                              hipStream_t stream)
{
    const float* x  = (const float*)d_in[0];
    const float* Wk = (const float*)d_in[1];
    const float* bk = (const float*)d_in[2];
    const float* Wq = (const float*)d_in[3];
    const float* bq = (const float*)d_in[4];
    const float* Wv = (const float*)d_in[5];
    const float* bv = (const float*)d_in[6];
    float* out = (float*)d_out;

    const size_t SZ = (size_t)2 * TT * DM;
    unsigned short* Qh  = (unsigned short*)d_ws;
    unsigned short* Khi = Qh + SZ;
    unsigned short* Klo = Khi + SZ;
    unsigned short* Vt  = Klo + SZ;
    unsigned short* Whi = Vt + SZ;
    unsigned short* Wlo = Whi + (size_t)3 * WN;

    wsplit<<<dim3(WN / 2048, 3), dim3(256), 0, stream>>>(Wq, Wk, Wv, Whi, Wlo);

    dim3 pgrid(2 * TT / 128, DM / 64, 3);
    proj_mfma<<<pgrid, dim3(256), 0, stream>>>(x, Whi, Wlo, bq, bk, bv,
                                               Qh, Khi, Klo, Vt);

    attn_mfma<<<dim3(512), dim3(256), 0, stream>>>(Qh, Khi, Klo, Vt, out);
}